// Round 1
// baseline (867.228 us; speedup 1.0000x reference)
//
#include <hip/hip_runtime.h>

#define N_NODES 100000
#define N_EDGES 1600000
#define N_GRAPHS 1024
#define F_IN 74
#define HID 100

#define CHUNK 1024
#define NCHUNK ((N_NODES + CHUNK - 1) / CHUNK)  // 98

// ---------------- CSR build ----------------

__global__ void k_hist(const int* __restrict__ dst, int* __restrict__ degcnt) {
    int e = blockIdx.x * blockDim.x + threadIdx.x;
    if (e < N_EDGES) atomicAdd(&degcnt[dst[e]], 1);
}

__global__ void k_scan1(const int* __restrict__ deg, int* __restrict__ csum) {
    __shared__ int lds[4];
    int b = blockIdx.x, t = threadIdx.x;
    int base = b * CHUNK + t * 4;
    int s = 0;
    #pragma unroll
    for (int i = 0; i < 4; ++i) {
        int idx = base + i;
        if (idx < N_NODES) s += deg[idx];
    }
    #pragma unroll
    for (int off = 32; off; off >>= 1) s += __shfl_down(s, off, 64);
    int lane = t & 63, w = t >> 6;
    if (lane == 0) lds[w] = s;
    __syncthreads();
    if (t == 0) {
        int tot = 0;
        for (int i = 0; i < 4; ++i) tot += lds[i];
        csum[b] = tot;
    }
}

__global__ void k_scan2(int* __restrict__ csum) {
    __shared__ int lds[NCHUNK];
    int t = threadIdx.x;
    if (t < NCHUNK) lds[t] = csum[t];
    __syncthreads();
    if (t == 0) {
        int run = 0;
        for (int i = 0; i < NCHUNK; ++i) { int v = lds[i]; lds[i] = run; run += v; }
    }
    __syncthreads();
    if (t < NCHUNK) csum[t] = lds[t];
}

__global__ void k_scan3(const int* __restrict__ deg, const int* __restrict__ csum,
                        int* __restrict__ row_ptr) {
    __shared__ int wsum[4];
    int b = blockIdx.x, t = threadIdx.x, lane = t & 63, w = t >> 6;
    int base = b * CHUNK + t * 4;
    int d[4];
    int s = 0;
    #pragma unroll
    for (int i = 0; i < 4; ++i) {
        int idx = base + i;
        d[i] = (idx < N_NODES) ? deg[idx] : 0;
        s += d[i];
    }
    int inc = s;
    #pragma unroll
    for (int off = 1; off < 64; off <<= 1) {
        int v = __shfl_up(inc, off, 64);
        if (lane >= off) inc += v;
    }
    if (lane == 63) wsum[w] = inc;
    int exc = inc - s;
    __syncthreads();
    int woff = 0;
    for (int i = 0; i < w; ++i) woff += wsum[i];
    int run = csum[b] + woff + exc;
    #pragma unroll
    for (int i = 0; i < 4; ++i) {
        int idx = base + i;
        if (idx < N_NODES) row_ptr[idx] = run;
        run += d[i];
    }
    if (b == 0 && t == 0) row_ptr[N_NODES] = N_EDGES;
}

__global__ void k_fill(const int* __restrict__ src, const int* __restrict__ dst,
                       const int* __restrict__ row_ptr, int* __restrict__ fillcnt,
                       int* __restrict__ csr) {
    int e = blockIdx.x * blockDim.x + threadIdx.x;
    if (e < N_EDGES) {
        int d = dst[e];
        int pos = atomicAdd(&fillcnt[d], 1);
        csr[row_ptr[d] + pos] = src[e];
    }
}

// ---------------- Mean aggregation (one wave per node) ----------------

template <int F, int LDIN>
__global__ void k_agg(const float* __restrict__ in, const int* __restrict__ row_ptr,
                      const int* __restrict__ csr, float* __restrict__ out) {
    int wid = threadIdx.x >> 6;
    int lane = threadIdx.x & 63;
    int v = blockIdx.x * 4 + wid;
    if (v >= N_NODES) return;
    int s = row_ptr[v], e = row_ptr[v + 1];
    float a0 = 0.f, a1 = 0.f;
    const bool has2 = (lane + 64) < F;
    for (int j = s; j < e; ++j) {
        int u = csr[j];
        const float* r = in + (long)u * LDIN;
        a0 += r[lane];
        if (has2) a1 += r[lane + 64];
    }
    float inv = 1.0f / fmaxf((float)(e - s), 1.0f);
    float* o = out + (long)v * HID;
    o[lane] = a0 * inv;
    if (has2) o[lane + 64] = a1 * inv;
}

// ---------------- Fused dual GEMM: C = relu(A@Ws + B@Wn + bias) ----------------
// A: [N_NODES, LDA] (self feats), B: [N_NODES, HID] (neigh feats, ld HID)
// Ws, Wn: [K, HID], bias: [HID], C: [N_NODES, HID]

template <int K, int LDA>
__global__ __launch_bounds__(256) void k_gemm(
    const float* __restrict__ A, const float* __restrict__ B,
    const float* __restrict__ Ws, const float* __restrict__ Wn,
    const float* __restrict__ bias, float* __restrict__ C) {
    const int TM = 32;
    __shared__ float As[TM][33], An[TM][33];
    __shared__ float WsS[32][HID], WnS[32][HID];
    int t = threadIdx.x;
    int tx = t & 15;   // column group
    int ty = t >> 4;   // row group: rows ty, ty+16
    int m0 = blockIdx.x * TM;

    float acc[2][8];
    #pragma unroll
    for (int r = 0; r < 2; ++r)
        #pragma unroll
        for (int j = 0; j < 8; ++j) acc[r][j] = 0.f;

    for (int k0 = 0; k0 < K; k0 += 32) {
        int kcn = (K - k0 < 32) ? (K - k0) : 32;
        // stage W chunk (zero-pad tail so inner loop can be fixed-length)
        for (int idx = t; idx < 32 * HID; idx += 256) {
            int kk = idx / HID, n = idx - kk * HID;
            float ws = 0.f, wn = 0.f;
            if (kk < kcn) {
                ws = Ws[(k0 + kk) * HID + n];
                wn = Wn[(k0 + kk) * HID + n];
            }
            WsS[kk][n] = ws;
            WnS[kk][n] = wn;
        }
        // stage A/B tiles (zero-pad tail)
        for (int idx = t; idx < TM * 32; idx += 256) {
            int r = idx >> 5, c = idx & 31;
            float va = 0.f, vb = 0.f;
            if (c < kcn) {
                va = A[(long)(m0 + r) * LDA + k0 + c];
                vb = B[(long)(m0 + r) * HID + k0 + c];
            }
            As[r][c] = va;
            An[r][c] = vb;
        }
        __syncthreads();
        #pragma unroll 4
        for (int kk = 0; kk < 32; ++kk) {
            float a0 = As[ty][kk], a1 = As[ty + 16][kk];
            float b0 = An[ty][kk], b1 = An[ty + 16][kk];
            #pragma unroll
            for (int j = 0; j < 4; ++j) {
                int p = tx + 16 * j;  // pair index, n = 2p
                if (p < 50) {
                    float2 ws = *(const float2*)&WsS[kk][2 * p];
                    float2 wn = *(const float2*)&WnS[kk][2 * p];
                    acc[0][2 * j]     += a0 * ws.x + b0 * wn.x;
                    acc[0][2 * j + 1] += a0 * ws.y + b0 * wn.y;
                    acc[1][2 * j]     += a1 * ws.x + b1 * wn.x;
                    acc[1][2 * j + 1] += a1 * ws.y + b1 * wn.y;
                }
            }
        }
        __syncthreads();
    }

    #pragma unroll
    for (int r = 0; r < 2; ++r) {
        int m = m0 + ty + r * 16;
        #pragma unroll
        for (int j = 0; j < 4; ++j) {
            int p = tx + 16 * j;
            if (p < 50) {
                int n = 2 * p;
                float v0 = acc[r][2 * j] + bias[n];
                float v1 = acc[r][2 * j + 1] + bias[n + 1];
                C[(long)m * HID + n] = fmaxf(v0, 0.f);
                C[(long)m * HID + n + 1] = fmaxf(v1, 0.f);
            }
        }
    }
}

// ---------------- Collapsed predictor head: w_eff[200], b_eff ----------------

__global__ void k_weff(const float* __restrict__ Wp1, const float* __restrict__ bp1,
                       const float* __restrict__ Wp2, const float* __restrict__ bp2,
                       float* __restrict__ weff) {
    int t = threadIdx.x;
    if (t < 200) {
        float s = 0.f;
        for (int k = 0; k < 64; ++k) s += Wp1[t * 64 + k] * Wp2[k];
        weff[t] = s;
    } else if (t == 200) {
        float s = bp2[0];
        for (int k = 0; k < 64; ++k) s += bp1[k] * Wp2[k];
        weff[200] = s;
    }
}

// ---------------- Readout: per-graph weighted sum + max, fused head ----------------

__global__ __launch_bounds__(128) void k_readout(
    const float* __restrict__ h, const int* __restrict__ graph_ids,
    const float* __restrict__ w_atom, const float* __restrict__ b_atom,
    const float* __restrict__ weff, float* __restrict__ out) {
    int g = blockIdx.x;
    int t = threadIdx.x, lane = t & 63, w = t >> 6;

    // boundaries via binary search (graph_ids sorted); uniform across block
    int s_, e_;
    {
        int l = 0, r = N_NODES;
        while (l < r) { int m = (l + r) >> 1; if (graph_ids[m] < g) l = m + 1; else r = m; }
        s_ = l;
        l = s_; r = N_NODES;
        while (l < r) { int m = (l + r) >> 1; if (graph_ids[m] < g + 1) l = m + 1; else r = m; }
        e_ = l;
    }

    float ba = b_atom[0];
    float wa0 = w_atom[lane];
    float wa1 = (lane < HID - 64) ? w_atom[lane + 64] : 0.f;
    float sum0 = 0.f, sum1 = 0.f, mx0 = 0.f, mx1 = 0.f;  // h >= 0 (relu), so 0-init max ok
    for (int i = s_ + w; i < e_; i += 2) {
        const float* r = h + (long)i * HID;
        float v0 = r[lane];
        float v1 = (lane < HID - 64) ? r[lane + 64] : 0.f;
        float p = v0 * wa0 + v1 * wa1;
        #pragma unroll
        for (int off = 32; off; off >>= 1) p += __shfl_xor(p, off, 64);
        float wt = 1.f / (1.f + __expf(-(p + ba)));
        sum0 += v0 * wt;
        sum1 += v1 * wt;
        mx0 = fmaxf(mx0, v0);
        mx1 = fmaxf(mx1, v1);
    }

    __shared__ float ssum[2][HID];
    __shared__ float smx[2][HID];
    ssum[w][lane] = sum0;
    smx[w][lane] = mx0;
    if (lane < HID - 64) {
        ssum[w][lane + 64] = sum1;
        smx[w][lane + 64] = mx1;
    }
    __syncthreads();

    float contrib = 0.f;
    if (t < HID) {
        float sumf = ssum[0][t] + ssum[1][t];
        float mxf = fmaxf(smx[0][t], smx[1][t]);
        contrib = sumf * weff[t] + mxf * weff[HID + t];
    }
    #pragma unroll
    for (int off = 32; off; off >>= 1) contrib += __shfl_xor(contrib, off, 64);
    __shared__ float red[2];
    if (lane == 0) red[w] = contrib;
    __syncthreads();
    if (t == 0) out[g] = red[0] + red[1] + weff[200];
}

// ---------------- launch ----------------

extern "C" void kernel_launch(void* const* d_in, const int* in_sizes, int n_in,
                              void* d_out, int out_size, void* d_ws, size_t ws_size,
                              hipStream_t stream) {
    const float* node_feats = (const float*)d_in[0];
    const int* src = (const int*)d_in[1];
    const int* dst = (const int*)d_in[2];
    const int* gid = (const int*)d_in[3];
    const float* Ws1 = (const float*)d_in[5];
    const float* Wn1 = (const float*)d_in[6];
    const float* b1 = (const float*)d_in[7];
    const float* Ws2 = (const float*)d_in[8];
    const float* Wn2 = (const float*)d_in[9];
    const float* b2 = (const float*)d_in[10];
    const float* w_atom = (const float*)d_in[11];
    const float* b_atom = (const float*)d_in[12];
    const float* Wp1 = (const float*)d_in[13];
    const float* bp1 = (const float*)d_in[14];
    const float* Wp2 = (const float*)d_in[15];
    const float* bp2 = (const float*)d_in[16];
    float* out = (float*)d_out;

    char* ws = (char*)d_ws;
    size_t off = 0;
    auto alloc = [&](size_t bytes) -> void* {
        void* p = (void*)(ws + off);
        off += (bytes + 255) & ~(size_t)255;
        return p;
    };
    int* degcnt = (int*)alloc(N_NODES * sizeof(int));
    int* fillcnt = (int*)alloc(N_NODES * sizeof(int));
    int* row_ptr = (int*)alloc((N_NODES + 1) * sizeof(int));
    int* csum = (int*)alloc(NCHUNK * sizeof(int));
    int* csr = (int*)alloc((size_t)N_EDGES * sizeof(int));
    float* hn = (float*)alloc((size_t)N_NODES * HID * sizeof(float));
    float* h1 = (float*)alloc((size_t)N_NODES * HID * sizeof(float));
    float* h2 = (float*)alloc((size_t)N_NODES * HID * sizeof(float));
    float* weff = (float*)alloc(256 * sizeof(float));

    hipMemsetAsync(degcnt, 0, N_NODES * sizeof(int), stream);
    hipMemsetAsync(fillcnt, 0, N_NODES * sizeof(int), stream);

    k_hist<<<(N_EDGES + 255) / 256, 256, 0, stream>>>(dst, degcnt);
    k_scan1<<<NCHUNK, 256, 0, stream>>>(degcnt, csum);
    k_scan2<<<1, 128, 0, stream>>>(csum);
    k_scan3<<<NCHUNK, 256, 0, stream>>>(degcnt, csum, row_ptr);
    k_fill<<<(N_EDGES + 255) / 256, 256, 0, stream>>>(src, dst, row_ptr, fillcnt, csr);

    k_agg<F_IN, F_IN><<<(N_NODES + 3) / 4, 256, 0, stream>>>(node_feats, row_ptr, csr, hn);
    k_gemm<F_IN, F_IN><<<N_NODES / 32, 256, 0, stream>>>(node_feats, hn, Ws1, Wn1, b1, h1);
    k_agg<HID, HID><<<(N_NODES + 3) / 4, 256, 0, stream>>>(h1, row_ptr, csr, hn);
    k_gemm<HID, HID><<<N_NODES / 32, 256, 0, stream>>>(h1, hn, Ws2, Wn2, b2, h2);

    k_weff<<<1, 256, 0, stream>>>(Wp1, bp1, Wp2, bp2, weff);
    k_readout<<<N_GRAPHS, 128, 0, stream>>>(h2, gid, w_atom, b_atom, weff, out);
}

// Round 3
// 687.314 us; speedup vs baseline: 1.2618x; 1.2618x over previous
//
#include <hip/hip_runtime.h>

#define N_NODES 100000
#define N_PAD   100096   // 782 blocks * 128 rows
#define N_EDGES 1600000
#define N_GRAPHS 1024
#define F_IN 74
#define HID 100

#define KP1 160   // 74+74 -> pad to 5*32
#define KP2 224   // 100+100 -> pad to 7*32

#define CHUNK 1024
#define NCHUNK ((N_NODES + CHUNK - 1) / CHUNK)  // 98

typedef __attribute__((ext_vector_type(8))) short short8;
typedef __attribute__((ext_vector_type(4))) float f32x4;

__device__ __forceinline__ unsigned short f2bf(float x) {
    union { float f; unsigned u; } c; c.f = x;
    unsigned u = c.u;
    unsigned r = (u + 0x7fffu + ((u >> 16) & 1u)) >> 16;
    return (unsigned short)r;
}
__device__ __forceinline__ float bf2f(unsigned short h) {
    union { unsigned u; float f; } c; c.u = ((unsigned)h) << 16;
    return c.f;
}

// ---------------- CSR build ----------------

__global__ void k_hist(const int* __restrict__ dst, int* __restrict__ degcnt) {
    int e = blockIdx.x * blockDim.x + threadIdx.x;
    if (e < N_EDGES) atomicAdd(&degcnt[dst[e]], 1);
}

__global__ void k_scan1(const int* __restrict__ deg, int* __restrict__ csum) {
    __shared__ int lds[4];
    int b = blockIdx.x, t = threadIdx.x;
    int base = b * CHUNK + t * 4;
    int s = 0;
    #pragma unroll
    for (int i = 0; i < 4; ++i) {
        int idx = base + i;
        if (idx < N_NODES) s += deg[idx];
    }
    #pragma unroll
    for (int off = 32; off; off >>= 1) s += __shfl_down(s, off, 64);
    int lane = t & 63, w = t >> 6;
    if (lane == 0) lds[w] = s;
    __syncthreads();
    if (t == 0) {
        int tot = 0;
        for (int i = 0; i < 4; ++i) tot += lds[i];
        csum[b] = tot;
    }
}

__global__ void k_scan2(int* __restrict__ csum) {
    __shared__ int lds[NCHUNK];
    int t = threadIdx.x;
    if (t < NCHUNK) lds[t] = csum[t];
    __syncthreads();
    if (t == 0) {
        int run = 0;
        for (int i = 0; i < NCHUNK; ++i) { int v = lds[i]; lds[i] = run; run += v; }
    }
    __syncthreads();
    if (t < NCHUNK) csum[t] = lds[t];
}

__global__ void k_scan3(const int* __restrict__ deg, const int* __restrict__ csum,
                        int* __restrict__ row_ptr) {
    __shared__ int wsum[4];
    int b = blockIdx.x, t = threadIdx.x, lane = t & 63, w = t >> 6;
    int base = b * CHUNK + t * 4;
    int d[4];
    int s = 0;
    #pragma unroll
    for (int i = 0; i < 4; ++i) {
        int idx = base + i;
        d[i] = (idx < N_NODES) ? deg[idx] : 0;
        s += d[i];
    }
    int inc = s;
    #pragma unroll
    for (int off = 1; off < 64; off <<= 1) {
        int v = __shfl_up(inc, off, 64);
        if (lane >= off) inc += v;
    }
    if (lane == 63) wsum[w] = inc;
    int exc = inc - s;
    __syncthreads();
    int woff = 0;
    for (int i = 0; i < w; ++i) woff += wsum[i];
    int run = csum[b] + woff + exc;
    #pragma unroll
    for (int i = 0; i < 4; ++i) {
        int idx = base + i;
        if (idx < N_NODES) row_ptr[idx] = run;
        run += d[i];
    }
    if (b == 0 && t == 0) row_ptr[N_NODES] = N_EDGES;
}

__global__ void k_fill(const int* __restrict__ src, const int* __restrict__ dst,
                       const int* __restrict__ row_ptr, int* __restrict__ fillcnt,
                       int* __restrict__ csr) {
    int e = blockIdx.x * blockDim.x + threadIdx.x;
    if (e < N_EDGES) {
        int d = dst[e];
        int pos = atomicAdd(&fillcnt[d], 1);
        csr[row_ptr[d] + pos] = src[e];
    }
}

// ---------------- Weight preconvert: Wt[col][k] = [Ws;Wn], bf16 hi/lo ----------------

template <int KP, int K1>
__global__ void k_wconv(const float* __restrict__ Ws, const float* __restrict__ Wn,
                        short* __restrict__ Whi, short* __restrict__ Wlo) {
    int idx = blockIdx.x * blockDim.x + threadIdx.x;
    if (idx >= 112 * KP) return;
    int col = idx / KP, k = idx - col * KP;
    float v = 0.f;
    if (col < HID) {
        if (k < K1) v = Ws[k * HID + col];
        else if (k < 2 * K1) v = Wn[(k - K1) * HID + col];
    }
    unsigned short hi = f2bf(v);
    unsigned short lo = f2bf(v - bf2f(hi));
    Whi[idx] = (short)hi;
    Wlo[idx] = (short)lo;
}

// ---------------- prep1: X1 = [bf16(feats) | bf16(mean-agg feats) | 0], hi/lo ----------------

__global__ void k_prep1(const float* __restrict__ feats, const int* __restrict__ row_ptr,
                        const int* __restrict__ csr,
                        short* __restrict__ Xhi, short* __restrict__ Xlo) {
    __shared__ float tmp[4][80];
    int wid = threadIdx.x >> 6, lane = threadIdx.x & 63;
    int v = blockIdx.x * 4 + wid;
    bool valid = v < N_NODES;
    if (valid) {
        int s = row_ptr[v], e = row_ptr[v + 1];
        float a0 = 0.f, a1 = 0.f;
        bool has2 = lane < (F_IN - 64);
        for (int j = s; j < e; ++j) {
            int u = csr[j];
            const float* r = feats + (size_t)u * F_IN;
            a0 += r[lane];
            if (has2) a1 += r[lane + 64];
        }
        float inv = 1.0f / fmaxf((float)(e - s), 1.0f);
        tmp[wid][lane] = a0 * inv;
        if (has2) tmp[wid][lane + 64] = a1 * inv;
    }
    __syncthreads();
    if (!valid) return;
    const float* selfr = feats + (size_t)v * F_IN;
    size_t base = (size_t)v * KP1;
    // col = lane (0..63): self feats
    {
        float x = selfr[lane];
        unsigned short hi = f2bf(x), lo = f2bf(x - bf2f(hi));
        Xhi[base + lane] = (short)hi; Xlo[base + lane] = (short)lo;
    }
    // col = lane+64 (64..127): self feats (col<74) else agg[col-74]
    {
        int col = lane + 64;
        float x = (col < F_IN) ? selfr[col] : tmp[wid][col - F_IN];
        unsigned short hi = f2bf(x), lo = f2bf(x - bf2f(hi));
        Xhi[base + col] = (short)hi; Xlo[base + col] = (short)lo;
    }
    // col = lane+128 (128..159): agg[col-74] if col<148 else 0
    if (lane < KP1 - 128) {
        int col = lane + 128;
        float x = (col < 74 + F_IN) ? tmp[wid][col - F_IN] : 0.f;
        unsigned short hi = f2bf(x), lo = f2bf(x - bf2f(hi));
        Xhi[base + col] = (short)hi; Xlo[base + col] = (short)lo;
    }
}

// ---------------- prep2: X2[:,100..223] = [bf16(mean-agg h1) | 0], hi/lo ----------------
// h1 lives in X2[:,0..99] as hi/lo bf16 (written by gemm1 epilogue)

__global__ void k_prep2(const int* __restrict__ row_ptr, const int* __restrict__ csr,
                        short* __restrict__ Xhi, short* __restrict__ Xlo) {
    __shared__ float tmp[4][100];
    int wid = threadIdx.x >> 6, lane = threadIdx.x & 63;
    int v = blockIdx.x * 4 + wid;
    bool valid = v < N_NODES;
    if (valid) {
        int s = row_ptr[v], e = row_ptr[v + 1];
        float a0 = 0.f, a1 = 0.f;
        bool has2 = lane < (HID - 64);
        for (int j = s; j < e; ++j) {
            size_t rb = (size_t)csr[j] * KP2;
            a0 += bf2f((unsigned short)Xhi[rb + lane]) + bf2f((unsigned short)Xlo[rb + lane]);
            if (has2)
                a1 += bf2f((unsigned short)Xhi[rb + lane + 64]) + bf2f((unsigned short)Xlo[rb + lane + 64]);
        }
        float inv = 1.0f / fmaxf((float)(e - s), 1.0f);
        tmp[wid][lane] = a0 * inv;
        if (has2) tmp[wid][lane + 64] = a1 * inv;
    }
    __syncthreads();
    if (!valid) return;
    size_t base = (size_t)v * KP2;
    // cols 100..223 map: lane+64 (>=100), lane+128, lane+192 (lane<32 only!)
    {
        int col = lane + 64;
        if (col >= HID) {
            float x = tmp[wid][col - HID];
            unsigned short hi = f2bf(x), lo = f2bf(x - bf2f(hi));
            Xhi[base + col] = (short)hi; Xlo[base + col] = (short)lo;
        }
    }
    {
        int col = lane + 128;  // f = col-100 = lane+28 in 28..91
        float x = tmp[wid][lane + 28];
        unsigned short hi = f2bf(x), lo = f2bf(x - bf2f(hi));
        Xhi[base + col] = (short)hi; Xlo[base + col] = (short)lo;
    }
    if (lane < KP2 - 192) {  // lane < 32: col in 192..223 ONLY (was OOB into next row!)
        int col = lane + 192;  // f = lane+92: valid if <100, else zero-pad
        float x = (lane < 8) ? tmp[wid][lane + 92] : 0.f;
        unsigned short hi = f2bf(x), lo = f2bf(x - bf2f(hi));
        Xhi[base + col] = (short)hi; Xlo[base + col] = (short)lo;
    }
}

// ---------------- MFMA GEMM: C = relu(X @ Wt^T + bias), bf16x3 split ----------------
// X: [N_PAD][KP] hi/lo bf16. Wt: [112][KP] hi/lo bf16 (col-major weights).
// LAST=false: write Y (=X2 cols 0..99) hi/lo. LAST=true: write Hout fp32 [N,100].

template <int KP, bool LAST>
__global__ __launch_bounds__(256) void k_mfma(
    const short* __restrict__ Xhi, const short* __restrict__ Xlo,
    const short* __restrict__ Wthi, const short* __restrict__ Wtlo,
    const float* __restrict__ bias,
    short* __restrict__ Yhi, short* __restrict__ Ylo,
    float* __restrict__ Hout) {
    int t = threadIdx.x;
    int wid = t >> 6, lane = t & 63;
    int quad = lane >> 4, lr = lane & 15;
    int rowbase = blockIdx.x * 128 + wid * 32;

    f32x4 acc[2][7];
    #pragma unroll
    for (int rf = 0; rf < 2; ++rf)
        #pragma unroll
        for (int n = 0; n < 7; ++n) acc[rf][n] = (f32x4){0.f, 0.f, 0.f, 0.f};

    const int NC = KP / 32;
    for (int c = 0; c < NC; ++c) {
        short8 ah[2], al[2], wh[7], wl[7];
        #pragma unroll
        for (int rf = 0; rf < 2; ++rf) {
            size_t off = (size_t)(rowbase + rf * 16 + lr) * KP + c * 32 + quad * 8;
            ah[rf] = *(const short8*)(Xhi + off);
            al[rf] = *(const short8*)(Xlo + off);
        }
        #pragma unroll
        for (int n = 0; n < 7; ++n) {
            size_t off = (size_t)(n * 16 + lr) * KP + c * 32 + quad * 8;
            wh[n] = *(const short8*)(Wthi + off);
            wl[n] = *(const short8*)(Wtlo + off);
        }
        #pragma unroll
        for (int rf = 0; rf < 2; ++rf)
            #pragma unroll
            for (int n = 0; n < 7; ++n) {
                acc[rf][n] = __builtin_amdgcn_mfma_f32_16x16x32_bf16(ah[rf], wh[n], acc[rf][n], 0, 0, 0);
                acc[rf][n] = __builtin_amdgcn_mfma_f32_16x16x32_bf16(ah[rf], wl[n], acc[rf][n], 0, 0, 0);
                acc[rf][n] = __builtin_amdgcn_mfma_f32_16x16x32_bf16(al[rf], wh[n], acc[rf][n], 0, 0, 0);
            }
    }

    #pragma unroll
    for (int rf = 0; rf < 2; ++rf) {
        #pragma unroll
        for (int n = 0; n < 7; ++n) {
            int col = n * 16 + lr;
            if (col < HID) {
                float bv = bias[col];
                #pragma unroll
                for (int r = 0; r < 4; ++r) {
                    int row = rowbase + rf * 16 + quad * 4 + r;
                    if (row < N_NODES) {
                        float v = fmaxf(acc[rf][n][r] + bv, 0.f);
                        if (LAST) {
                            Hout[(size_t)row * HID + col] = v;
                        } else {
                            unsigned short hi = f2bf(v), lo = f2bf(v - bf2f(hi));
                            Yhi[(size_t)row * KP2 + col] = (short)hi;
                            Ylo[(size_t)row * KP2 + col] = (short)lo;
                        }
                    }
                }
            }
        }
    }
}

// ---------------- Collapsed predictor head: w_eff[200], b_eff ----------------

__global__ void k_weff(const float* __restrict__ Wp1, const float* __restrict__ bp1,
                       const float* __restrict__ Wp2, const float* __restrict__ bp2,
                       float* __restrict__ weff) {
    int t = threadIdx.x;
    if (t < 200) {
        float s = 0.f;
        for (int k = 0; k < 64; ++k) s += Wp1[t * 64 + k] * Wp2[k];
        weff[t] = s;
    } else if (t == 200) {
        float s = bp2[0];
        for (int k = 0; k < 64; ++k) s += bp1[k] * Wp2[k];
        weff[200] = s;
    }
}

// ---------------- Readout: per-graph weighted sum + max, fused head ----------------

__global__ __launch_bounds__(128) void k_readout(
    const float* __restrict__ h, const int* __restrict__ graph_ids,
    const float* __restrict__ w_atom, const float* __restrict__ b_atom,
    const float* __restrict__ weff, float* __restrict__ out) {
    int g = blockIdx.x;
    int t = threadIdx.x, lane = t & 63, w = t >> 6;

    int s_, e_;
    {
        int l = 0, r = N_NODES;
        while (l < r) { int m = (l + r) >> 1; if (graph_ids[m] < g) l = m + 1; else r = m; }
        s_ = l;
        l = s_; r = N_NODES;
        while (l < r) { int m = (l + r) >> 1; if (graph_ids[m] < g + 1) l = m + 1; else r = m; }
        e_ = l;
    }

    float ba = b_atom[0];
    float wa0 = w_atom[lane];
    float wa1 = (lane < HID - 64) ? w_atom[lane + 64] : 0.f;
    float sum0 = 0.f, sum1 = 0.f, mx0 = 0.f, mx1 = 0.f;  // h >= 0 (relu)
    for (int i = s_ + w; i < e_; i += 2) {
        const float* r = h + (size_t)i * HID;
        float v0 = r[lane];
        float v1 = (lane < HID - 64) ? r[lane + 64] : 0.f;
        float p = v0 * wa0 + v1 * wa1;
        #pragma unroll
        for (int off = 32; off; off >>= 1) p += __shfl_xor(p, off, 64);
        float wt = 1.f / (1.f + __expf(-(p + ba)));
        sum0 += v0 * wt;
        sum1 += v1 * wt;
        mx0 = fmaxf(mx0, v0);
        mx1 = fmaxf(mx1, v1);
    }

    __shared__ float ssum[2][HID];
    __shared__ float smx[2][HID];
    ssum[w][lane] = sum0;
    smx[w][lane] = mx0;
    if (lane < HID - 64) {
        ssum[w][lane + 64] = sum1;
        smx[w][lane + 64] = mx1;
    }
    __syncthreads();

    float contrib = 0.f;
    if (t < HID) {
        float sumf = ssum[0][t] + ssum[1][t];
        float mxf = fmaxf(smx[0][t], smx[1][t]);
        contrib = sumf * weff[t] + mxf * weff[HID + t];
    }
    #pragma unroll
    for (int off = 32; off; off >>= 1) contrib += __shfl_xor(contrib, off, 64);
    __shared__ float red[2];
    if (lane == 0) red[w] = contrib;
    __syncthreads();
    if (t == 0) out[g] = red[0] + red[1] + weff[200];
}

// ---------------- launch ----------------

extern "C" void kernel_launch(void* const* d_in, const int* in_sizes, int n_in,
                              void* d_out, int out_size, void* d_ws, size_t ws_size,
                              hipStream_t stream) {
    const float* node_feats = (const float*)d_in[0];
    const int* src = (const int*)d_in[1];
    const int* dst = (const int*)d_in[2];
    const int* gid = (const int*)d_in[3];
    const float* Ws1 = (const float*)d_in[5];
    const float* Wn1 = (const float*)d_in[6];
    const float* b1 = (const float*)d_in[7];
    const float* Ws2 = (const float*)d_in[8];
    const float* Wn2 = (const float*)d_in[9];
    const float* b2 = (const float*)d_in[10];
    const float* w_atom = (const float*)d_in[11];
    const float* b_atom = (const float*)d_in[12];
    const float* Wp1 = (const float*)d_in[13];
    const float* bp1 = (const float*)d_in[14];
    const float* Wp2 = (const float*)d_in[15];
    const float* bp2 = (const float*)d_in[16];
    float* out = (float*)d_out;

    char* ws = (char*)d_ws;
    size_t off = 0;
    auto alloc = [&](size_t bytes) -> void* {
        void* p = (void*)(ws + off);
        off += (bytes + 255) & ~(size_t)255;
        return p;
    };
    int* degcnt = (int*)alloc(N_NODES * sizeof(int));
    int* fillcnt = (int*)alloc(N_NODES * sizeof(int));
    int* row_ptr = (int*)alloc((N_NODES + 1) * sizeof(int));
    int* csum = (int*)alloc(NCHUNK * sizeof(int));
    int* csr = (int*)alloc((size_t)N_EDGES * sizeof(int));
    short* X1hi = (short*)alloc((size_t)N_PAD * KP1 * sizeof(short));
    short* X1lo = (short*)alloc((size_t)N_PAD * KP1 * sizeof(short));
    short* X2hi = (short*)alloc((size_t)N_PAD * KP2 * sizeof(short));
    short* X2lo = (short*)alloc((size_t)N_PAD * KP2 * sizeof(short));
    short* Wt1hi = (short*)alloc(112 * KP1 * sizeof(short));
    short* Wt1lo = (short*)alloc(112 * KP1 * sizeof(short));
    short* Wt2hi = (short*)alloc(112 * KP2 * sizeof(short));
    short* Wt2lo = (short*)alloc(112 * KP2 * sizeof(short));
    float* weff = (float*)alloc(256 * sizeof(float));
    // h2 fp32 [N,100] aliases X1 (X1 dead after gemm1; X1hi+X1lo = 64MB > 40MB)
    float* h2 = (float*)X1hi;

    hipMemsetAsync(degcnt, 0, N_NODES * sizeof(int), stream);
    hipMemsetAsync(fillcnt, 0, N_NODES * sizeof(int), stream);

    k_hist<<<(N_EDGES + 255) / 256, 256, 0, stream>>>(dst, degcnt);
    k_scan1<<<NCHUNK, 256, 0, stream>>>(degcnt, csum);
    k_scan2<<<1, 128, 0, stream>>>(csum);
    k_scan3<<<NCHUNK, 256, 0, stream>>>(degcnt, csum, row_ptr);
    k_fill<<<(N_EDGES + 255) / 256, 256, 0, stream>>>(src, dst, row_ptr, fillcnt, csr);

    k_wconv<KP1, F_IN><<<(112 * KP1 + 255) / 256, 256, 0, stream>>>(Ws1, Wn1, Wt1hi, Wt1lo);
    k_wconv<KP2, HID><<<(112 * KP2 + 255) / 256, 256, 0, stream>>>(Ws2, Wn2, Wt2hi, Wt2lo);

    k_prep1<<<(N_NODES + 3) / 4, 256, 0, stream>>>(node_feats, row_ptr, csr, X1hi, X1lo);
    k_mfma<KP1, false><<<N_PAD / 128, 256, 0, stream>>>(X1hi, X1lo, Wt1hi, Wt1lo, b1,
                                                        X2hi, X2lo, nullptr);
    k_prep2<<<(N_NODES + 3) / 4, 256, 0, stream>>>(row_ptr, csr, X2hi, X2lo);
    k_mfma<KP2, true><<<N_PAD / 128, 256, 0, stream>>>(X2hi, X2lo, Wt2hi, Wt2lo, b2,
                                                       nullptr, nullptr, h2);

    k_weff<<<1, 256, 0, stream>>>(Wp1, bp1, Wp2, bp2, weff);
    k_readout<<<N_GRAPHS, 128, 0, stream>>>(h2, gid, w_atom, b_atom, weff, out);
}

// Round 4
// 529.171 us; speedup vs baseline: 1.6388x; 1.2989x over previous
//
#include <hip/hip_runtime.h>

#define N_NODES 100000
#define N_PAD   100096   // 782 blocks * 128 rows
#define N_EDGES 1600000
#define N_GRAPHS 1024
#define F_IN 74
#define HID 100

#define KP1 160   // 74+74 -> pad to 5*32
#define KP2 224   // 100+100 -> pad to 7*32

#define FBF_LD 80   // bf16 feats copy row stride (shorts)
#define H1C_LD 128  // bf16 h1 copy row stride (shorts), 256B aligned rows

#define CHUNK 1024
#define NCHUNK ((N_NODES + CHUNK - 1) / CHUNK)  // 98

typedef __attribute__((ext_vector_type(8))) short short8;
typedef __attribute__((ext_vector_type(4))) float f32x4;

__device__ __forceinline__ unsigned short f2bf(float x) {
    union { float f; unsigned u; } c; c.f = x;
    unsigned u = c.u;
    unsigned r = (u + 0x7fffu + ((u >> 16) & 1u)) >> 16;
    return (unsigned short)r;
}
__device__ __forceinline__ float bf2f(unsigned short h) {
    union { unsigned u; float f; } c; c.u = ((unsigned)h) << 16;
    return c.f;
}

// ---------------- CSR build ----------------

__global__ void k_hist(const int* __restrict__ dst, int* __restrict__ degcnt) {
    int e = blockIdx.x * blockDim.x + threadIdx.x;
    if (e < N_EDGES) atomicAdd(&degcnt[dst[e]], 1);
}

__global__ void k_scan1(const int* __restrict__ deg, int* __restrict__ csum) {
    __shared__ int lds[4];
    int b = blockIdx.x, t = threadIdx.x;
    int base = b * CHUNK + t * 4;
    int s = 0;
    #pragma unroll
    for (int i = 0; i < 4; ++i) {
        int idx = base + i;
        if (idx < N_NODES) s += deg[idx];
    }
    #pragma unroll
    for (int off = 32; off; off >>= 1) s += __shfl_down(s, off, 64);
    int lane = t & 63, w = t >> 6;
    if (lane == 0) lds[w] = s;
    __syncthreads();
    if (t == 0) {
        int tot = 0;
        for (int i = 0; i < 4; ++i) tot += lds[i];
        csum[b] = tot;
    }
}

__global__ void k_scan2(int* __restrict__ csum) {
    __shared__ int lds[NCHUNK];
    int t = threadIdx.x;
    if (t < NCHUNK) lds[t] = csum[t];
    __syncthreads();
    if (t == 0) {
        int run = 0;
        for (int i = 0; i < NCHUNK; ++i) { int v = lds[i]; lds[i] = run; run += v; }
    }
    __syncthreads();
    if (t < NCHUNK) csum[t] = lds[t];
}

__global__ void k_scan3(const int* __restrict__ deg, const int* __restrict__ csum,
                        int* __restrict__ row_ptr) {
    __shared__ int wsum[4];
    int b = blockIdx.x, t = threadIdx.x, lane = t & 63, w = t >> 6;
    int base = b * CHUNK + t * 4;
    int d[4];
    int s = 0;
    #pragma unroll
    for (int i = 0; i < 4; ++i) {
        int idx = base + i;
        d[i] = (idx < N_NODES) ? deg[idx] : 0;
        s += d[i];
    }
    int inc = s;
    #pragma unroll
    for (int off = 1; off < 64; off <<= 1) {
        int v = __shfl_up(inc, off, 64);
        if (lane >= off) inc += v;
    }
    if (lane == 63) wsum[w] = inc;
    int exc = inc - s;
    __syncthreads();
    int woff = 0;
    for (int i = 0; i < w; ++i) woff += wsum[i];
    int run = csum[b] + woff + exc;
    #pragma unroll
    for (int i = 0; i < 4; ++i) {
        int idx = base + i;
        if (idx < N_NODES) row_ptr[idx] = run;
        run += d[i];
    }
    if (b == 0 && t == 0) row_ptr[N_NODES] = N_EDGES;
}

__global__ void k_fill(const int* __restrict__ src, const int* __restrict__ dst,
                       const int* __restrict__ row_ptr, int* __restrict__ fillcnt,
                       int* __restrict__ csr) {
    int e = blockIdx.x * blockDim.x + threadIdx.x;
    if (e < N_EDGES) {
        int d = dst[e];
        int pos = atomicAdd(&fillcnt[d], 1);
        csr[row_ptr[d] + pos] = src[e];
    }
}

// ---------------- feats -> bf16 padded copy [N][80] ----------------

__global__ void k_feats_bf(const float* __restrict__ feats, short* __restrict__ fbf) {
    int idx = blockIdx.x * blockDim.x + threadIdx.x;
    if (idx >= N_NODES * FBF_LD) return;
    int n = idx / FBF_LD, col = idx - n * FBF_LD;
    float v = (col < F_IN) ? feats[(size_t)n * F_IN + col] : 0.f;
    fbf[idx] = (short)f2bf(v);
}

// ---------------- Weight preconvert: Wt[col][k] = [Ws;Wn], bf16 hi/lo ----------------

template <int KP, int K1>
__global__ void k_wconv(const float* __restrict__ Ws, const float* __restrict__ Wn,
                        short* __restrict__ Whi, short* __restrict__ Wlo) {
    int idx = blockIdx.x * blockDim.x + threadIdx.x;
    if (idx >= 112 * KP) return;
    int col = idx / KP, k = idx - col * KP;
    float v = 0.f;
    if (col < HID) {
        if (k < K1) v = Ws[k * HID + col];
        else if (k < 2 * K1) v = Wn[(k - K1) * HID + col];
    }
    unsigned short hi = f2bf(v);
    unsigned short lo = f2bf(v - bf2f(hi));
    Whi[idx] = (short)hi;
    Wlo[idx] = (short)lo;
}

// ---------------- prep1: X1 = [hi/lo(feats) | hi/lo(mean-agg bf16 feats) | 0] ----------------
// Gather from fbf [N][80] bf16: lane<37 loads one uint (2 feats). 256B (2 lines) per edge.

__global__ void k_prep1(const float* __restrict__ feats, const short* __restrict__ fbf,
                        const int* __restrict__ row_ptr, const int* __restrict__ csr,
                        short* __restrict__ Xhi, short* __restrict__ Xlo) {
    __shared__ float tmp[4][80];
    int wid = threadIdx.x >> 6, lane = threadIdx.x & 63;
    int v = blockIdx.x * 4 + wid;
    bool valid = v < N_NODES;
    if (valid && lane < 37) {
        int s = row_ptr[v], e = row_ptr[v + 1];
        const unsigned* fu = (const unsigned*)fbf;
        float a0 = 0.f, a1 = 0.f, b0 = 0.f, b1 = 0.f;
        int j = s;
        for (; j + 1 < e; j += 2) {
            unsigned w0 = fu[(size_t)csr[j] * (FBF_LD / 2) + lane];
            unsigned w1 = fu[(size_t)csr[j + 1] * (FBF_LD / 2) + lane];
            a0 += bf2f((unsigned short)(w0 & 0xffff));
            a1 += bf2f((unsigned short)(w0 >> 16));
            b0 += bf2f((unsigned short)(w1 & 0xffff));
            b1 += bf2f((unsigned short)(w1 >> 16));
        }
        if (j < e) {
            unsigned w0 = fu[(size_t)csr[j] * (FBF_LD / 2) + lane];
            a0 += bf2f((unsigned short)(w0 & 0xffff));
            a1 += bf2f((unsigned short)(w0 >> 16));
        }
        float inv = 1.0f / fmaxf((float)(e - s), 1.0f);
        tmp[wid][2 * lane] = (a0 + b0) * inv;
        tmp[wid][2 * lane + 1] = (a1 + b1) * inv;
    }
    __syncthreads();
    if (!valid) return;
    const float* selfr = feats + (size_t)v * F_IN;
    size_t base = (size_t)v * KP1;
    // col = lane (0..63): self feats
    {
        float x = selfr[lane];
        unsigned short hi = f2bf(x), lo = f2bf(x - bf2f(hi));
        Xhi[base + lane] = (short)hi; Xlo[base + lane] = (short)lo;
    }
    // col = lane+64 (64..127): self feats (col<74) else agg[col-74]
    {
        int col = lane + 64;
        float x = (col < F_IN) ? selfr[col] : tmp[wid][col - F_IN];
        unsigned short hi = f2bf(x), lo = f2bf(x - bf2f(hi));
        Xhi[base + col] = (short)hi; Xlo[base + col] = (short)lo;
    }
    // col = lane+128 (128..159): agg[col-74] if col<148 else 0
    if (lane < KP1 - 128) {
        int col = lane + 128;
        float x = (col < 74 + F_IN) ? tmp[wid][col - F_IN] : 0.f;
        unsigned short hi = f2bf(x), lo = f2bf(x - bf2f(hi));
        Xhi[base + col] = (short)hi; Xlo[base + col] = (short)lo;
    }
}

// ---------------- prep2: X2[:,100..223] = [hi/lo(mean-agg h1c) | 0] ----------------
// Gather from h1c [N][128] bf16 (cols 0..99 valid): lane<50 loads one uint. 256B/edge.

__global__ void k_prep2(const short* __restrict__ h1c, const int* __restrict__ row_ptr,
                        const int* __restrict__ csr,
                        short* __restrict__ Xhi, short* __restrict__ Xlo) {
    __shared__ float tmp[4][100];
    int wid = threadIdx.x >> 6, lane = threadIdx.x & 63;
    int v = blockIdx.x * 4 + wid;
    bool valid = v < N_NODES;
    if (valid && lane < 50) {
        int s = row_ptr[v], e = row_ptr[v + 1];
        const unsigned* hu = (const unsigned*)h1c;
        float a0 = 0.f, a1 = 0.f, b0 = 0.f, b1 = 0.f;
        int j = s;
        for (; j + 1 < e; j += 2) {
            unsigned w0 = hu[(size_t)csr[j] * (H1C_LD / 2) + lane];
            unsigned w1 = hu[(size_t)csr[j + 1] * (H1C_LD / 2) + lane];
            a0 += bf2f((unsigned short)(w0 & 0xffff));
            a1 += bf2f((unsigned short)(w0 >> 16));
            b0 += bf2f((unsigned short)(w1 & 0xffff));
            b1 += bf2f((unsigned short)(w1 >> 16));
        }
        if (j < e) {
            unsigned w0 = hu[(size_t)csr[j] * (H1C_LD / 2) + lane];
            a0 += bf2f((unsigned short)(w0 & 0xffff));
            a1 += bf2f((unsigned short)(w0 >> 16));
        }
        float inv = 1.0f / fmaxf((float)(e - s), 1.0f);
        tmp[wid][2 * lane] = (a0 + b0) * inv;
        tmp[wid][2 * lane + 1] = (a1 + b1) * inv;
    }
    __syncthreads();
    if (!valid) return;
    size_t base = (size_t)v * KP2;
    // cols 100..223 map: lane+64 (>=100), lane+128, lane+192 (lane<32 only)
    {
        int col = lane + 64;
        if (col >= HID) {
            float x = tmp[wid][col - HID];
            unsigned short hi = f2bf(x), lo = f2bf(x - bf2f(hi));
            Xhi[base + col] = (short)hi; Xlo[base + col] = (short)lo;
        }
    }
    {
        int col = lane + 128;  // f = lane+28 in 28..91
        float x = tmp[wid][lane + 28];
        unsigned short hi = f2bf(x), lo = f2bf(x - bf2f(hi));
        Xhi[base + col] = (short)hi; Xlo[base + col] = (short)lo;
    }
    if (lane < KP2 - 192) {  // lane < 32: col in 192..223 only
        int col = lane + 192;  // f = lane+92: valid if <100, else zero-pad
        float x = (lane < 8) ? tmp[wid][lane + 92] : 0.f;
        unsigned short hi = f2bf(x), lo = f2bf(x - bf2f(hi));
        Xhi[base + col] = (short)hi; Xlo[base + col] = (short)lo;
    }
}

// ---------------- MFMA GEMM: C = relu(X @ Wt^T + bias), bf16x3 split ----------------
// LAST=false: write Y (=X2 cols 0..99) hi/lo + h1c bf16 copy. LAST=true: write Hout fp32.

template <int KP, bool LAST>
__global__ __launch_bounds__(256) void k_mfma(
    const short* __restrict__ Xhi, const short* __restrict__ Xlo,
    const short* __restrict__ Wthi, const short* __restrict__ Wtlo,
    const float* __restrict__ bias,
    short* __restrict__ Yhi, short* __restrict__ Ylo, short* __restrict__ h1c,
    float* __restrict__ Hout) {
    int t = threadIdx.x;
    int wid = t >> 6, lane = t & 63;
    int quad = lane >> 4, lr = lane & 15;
    int rowbase = blockIdx.x * 128 + wid * 32;

    f32x4 acc[2][7];
    #pragma unroll
    for (int rf = 0; rf < 2; ++rf)
        #pragma unroll
        for (int n = 0; n < 7; ++n) acc[rf][n] = (f32x4){0.f, 0.f, 0.f, 0.f};

    const int NC = KP / 32;
    for (int c = 0; c < NC; ++c) {
        short8 ah[2], al[2], wh[7], wl[7];
        #pragma unroll
        for (int rf = 0; rf < 2; ++rf) {
            size_t off = (size_t)(rowbase + rf * 16 + lr) * KP + c * 32 + quad * 8;
            ah[rf] = *(const short8*)(Xhi + off);
            al[rf] = *(const short8*)(Xlo + off);
        }
        #pragma unroll
        for (int n = 0; n < 7; ++n) {
            size_t off = (size_t)(n * 16 + lr) * KP + c * 32 + quad * 8;
            wh[n] = *(const short8*)(Wthi + off);
            wl[n] = *(const short8*)(Wtlo + off);
        }
        #pragma unroll
        for (int rf = 0; rf < 2; ++rf)
            #pragma unroll
            for (int n = 0; n < 7; ++n) {
                acc[rf][n] = __builtin_amdgcn_mfma_f32_16x16x32_bf16(ah[rf], wh[n], acc[rf][n], 0, 0, 0);
                acc[rf][n] = __builtin_amdgcn_mfma_f32_16x16x32_bf16(ah[rf], wl[n], acc[rf][n], 0, 0, 0);
                acc[rf][n] = __builtin_amdgcn_mfma_f32_16x16x32_bf16(al[rf], wh[n], acc[rf][n], 0, 0, 0);
            }
    }

    #pragma unroll
    for (int rf = 0; rf < 2; ++rf) {
        #pragma unroll
        for (int n = 0; n < 7; ++n) {
            int col = n * 16 + lr;
            if (col < HID) {
                float bv = bias[col];
                #pragma unroll
                for (int r = 0; r < 4; ++r) {
                    int row = rowbase + rf * 16 + quad * 4 + r;
                    if (row < N_NODES) {
                        float v = fmaxf(acc[rf][n][r] + bv, 0.f);
                        if (LAST) {
                            Hout[(size_t)row * HID + col] = v;
                        } else {
                            unsigned short hi = f2bf(v), lo = f2bf(v - bf2f(hi));
                            Yhi[(size_t)row * KP2 + col] = (short)hi;
                            Ylo[(size_t)row * KP2 + col] = (short)lo;
                            h1c[(size_t)row * H1C_LD + col] = (short)hi;
                        }
                    }
                }
            }
        }
    }
}

// ---------------- Collapsed predictor head: w_eff[200], b_eff ----------------

__global__ void k_weff(const float* __restrict__ Wp1, const float* __restrict__ bp1,
                       const float* __restrict__ Wp2, const float* __restrict__ bp2,
                       float* __restrict__ weff) {
    int t = threadIdx.x;
    if (t < 200) {
        float s = 0.f;
        for (int k = 0; k < 64; ++k) s += Wp1[t * 64 + k] * Wp2[k];
        weff[t] = s;
    } else if (t == 200) {
        float s = bp2[0];
        for (int k = 0; k < 64; ++k) s += bp1[k] * Wp2[k];
        weff[200] = s;
    }
}

// ---------------- Readout: per-graph weighted sum + max, fused head ----------------

__global__ __launch_bounds__(128) void k_readout(
    const float* __restrict__ h, const int* __restrict__ graph_ids,
    const float* __restrict__ w_atom, const float* __restrict__ b_atom,
    const float* __restrict__ weff, float* __restrict__ out) {
    int g = blockIdx.x;
    int t = threadIdx.x, lane = t & 63, w = t >> 6;

    int s_, e_;
    {
        int l = 0, r = N_NODES;
        while (l < r) { int m = (l + r) >> 1; if (graph_ids[m] < g) l = m + 1; else r = m; }
        s_ = l;
        l = s_; r = N_NODES;
        while (l < r) { int m = (l + r) >> 1; if (graph_ids[m] < g + 1) l = m + 1; else r = m; }
        e_ = l;
    }

    float ba = b_atom[0];
    float wa0 = w_atom[lane];
    float wa1 = (lane < HID - 64) ? w_atom[lane + 64] : 0.f;
    float sum0 = 0.f, sum1 = 0.f, mx0 = 0.f, mx1 = 0.f;  // h >= 0 (relu)
    for (int i = s_ + w; i < e_; i += 2) {
        const float* r = h + (size_t)i * HID;
        float v0 = r[lane];
        float v1 = (lane < HID - 64) ? r[lane + 64] : 0.f;
        float p = v0 * wa0 + v1 * wa1;
        #pragma unroll
        for (int off = 32; off; off >>= 1) p += __shfl_xor(p, off, 64);
        float wt = 1.f / (1.f + __expf(-(p + ba)));
        sum0 += v0 * wt;
        sum1 += v1 * wt;
        mx0 = fmaxf(mx0, v0);
        mx1 = fmaxf(mx1, v1);
    }

    __shared__ float ssum[2][HID];
    __shared__ float smx[2][HID];
    ssum[w][lane] = sum0;
    smx[w][lane] = mx0;
    if (lane < HID - 64) {
        ssum[w][lane + 64] = sum1;
        smx[w][lane + 64] = mx1;
    }
    __syncthreads();

    float contrib = 0.f;
    if (t < HID) {
        float sumf = ssum[0][t] + ssum[1][t];
        float mxf = fmaxf(smx[0][t], smx[1][t]);
        contrib = sumf * weff[t] + mxf * weff[HID + t];
    }
    #pragma unroll
    for (int off = 32; off; off >>= 1) contrib += __shfl_xor(contrib, off, 64);
    __shared__ float red[2];
    if (lane == 0) red[w] = contrib;
    __syncthreads();
    if (t == 0) out[g] = red[0] + red[1] + weff[200];
}

// ---------------- launch ----------------

extern "C" void kernel_launch(void* const* d_in, const int* in_sizes, int n_in,
                              void* d_out, int out_size, void* d_ws, size_t ws_size,
                              hipStream_t stream) {
    const float* node_feats = (const float*)d_in[0];
    const int* src = (const int*)d_in[1];
    const int* dst = (const int*)d_in[2];
    const int* gid = (const int*)d_in[3];
    const float* Ws1 = (const float*)d_in[5];
    const float* Wn1 = (const float*)d_in[6];
    const float* b1 = (const float*)d_in[7];
    const float* Ws2 = (const float*)d_in[8];
    const float* Wn2 = (const float*)d_in[9];
    const float* b2 = (const float*)d_in[10];
    const float* w_atom = (const float*)d_in[11];
    const float* b_atom = (const float*)d_in[12];
    const float* Wp1 = (const float*)d_in[13];
    const float* bp1 = (const float*)d_in[14];
    const float* Wp2 = (const float*)d_in[15];
    const float* bp2 = (const float*)d_in[16];
    float* out = (float*)d_out;

    char* ws = (char*)d_ws;
    size_t off = 0;
    auto alloc = [&](size_t bytes) -> void* {
        void* p = (void*)(ws + off);
        off += (bytes + 255) & ~(size_t)255;
        return p;
    };
    int* degcnt = (int*)alloc(N_NODES * sizeof(int));
    int* fillcnt = (int*)alloc(N_NODES * sizeof(int));
    int* row_ptr = (int*)alloc((N_NODES + 1) * sizeof(int));
    int* csum = (int*)alloc(NCHUNK * sizeof(int));
    int* csr = (int*)alloc((size_t)N_EDGES * sizeof(int));
    short* X1hi = (short*)alloc((size_t)N_PAD * KP1 * sizeof(short));
    short* X1lo = (short*)alloc((size_t)N_PAD * KP1 * sizeof(short));
    short* X2hi = (short*)alloc((size_t)N_PAD * KP2 * sizeof(short));
    short* X2lo = (short*)alloc((size_t)N_PAD * KP2 * sizeof(short));
    short* h1c = (short*)alloc((size_t)N_NODES * H1C_LD * sizeof(short));
    short* Wt1hi = (short*)alloc(112 * KP1 * sizeof(short));
    short* Wt1lo = (short*)alloc(112 * KP1 * sizeof(short));
    short* Wt2hi = (short*)alloc(112 * KP2 * sizeof(short));
    short* Wt2lo = (short*)alloc(112 * KP2 * sizeof(short));
    float* weff = (float*)alloc(256 * sizeof(float));
    // fbf (16MB) aliases X2hi (44.8MB): fbf dead before gemm1 writes X2hi.
    short* fbf = X2hi;
    // h2 fp32 [N,100] aliases X1hi (X1 dead after gemm1).
    float* h2 = (float*)X1hi;

    hipMemsetAsync(degcnt, 0, N_NODES * sizeof(int), stream);
    hipMemsetAsync(fillcnt, 0, N_NODES * sizeof(int), stream);

    k_hist<<<(N_EDGES + 255) / 256, 256, 0, stream>>>(dst, degcnt);
    k_scan1<<<NCHUNK, 256, 0, stream>>>(degcnt, csum);
    k_scan2<<<1, 128, 0, stream>>>(csum);
    k_scan3<<<NCHUNK, 256, 0, stream>>>(degcnt, csum, row_ptr);
    k_fill<<<(N_EDGES + 255) / 256, 256, 0, stream>>>(src, dst, row_ptr, fillcnt, csr);

    k_feats_bf<<<(N_NODES * FBF_LD + 255) / 256, 256, 0, stream>>>(node_feats, fbf);
    k_wconv<KP1, F_IN><<<(112 * KP1 + 255) / 256, 256, 0, stream>>>(Ws1, Wn1, Wt1hi, Wt1lo);
    k_wconv<KP2, HID><<<(112 * KP2 + 255) / 256, 256, 0, stream>>>(Ws2, Wn2, Wt2hi, Wt2lo);

    k_prep1<<<(N_NODES + 3) / 4, 256, 0, stream>>>(node_feats, fbf, row_ptr, csr, X1hi, X1lo);
    k_mfma<KP1, false><<<N_PAD / 128, 256, 0, stream>>>(X1hi, X1lo, Wt1hi, Wt1lo, b1,
                                                        X2hi, X2lo, h1c, nullptr);
    k_prep2<<<(N_NODES + 3) / 4, 256, 0, stream>>>(h1c, row_ptr, csr, X2hi, X2lo);
    k_mfma<KP2, true><<<N_PAD / 128, 256, 0, stream>>>(X2hi, X2lo, Wt2hi, Wt2lo, b2,
                                                       nullptr, nullptr, nullptr, h2);

    k_weff<<<1, 256, 0, stream>>>(Wp1, bp1, Wp2, bp2, weff);
    k_readout<<<N_GRAPHS, 128, 0, stream>>>(h2, gid, w_atom, b_atom, weff, out);
}

// Round 5
// 464.146 us; speedup vs baseline: 1.8684x; 1.1401x over previous
//
#include <hip/hip_runtime.h>

#define N_NODES 100000
#define N_PAD   100096   // 782 blocks * 128 rows
#define N_EDGES 1600000
#define N_GRAPHS 1024
#define F_IN 74
#define HID 100

#define KP1 160   // 74+74 -> pad to 5*32
#define KP2 224   // 100+100 -> pad to 7*32

#define FBF_LD 80   // bf16 feats copy row stride (shorts)
#define H1C_LD 128  // bf16 h1 copy row stride (shorts), 256B aligned rows

#define CHUNK 1024
#define NCHUNK ((N_NODES + CHUNK - 1) / CHUNK)  // 98

typedef __attribute__((ext_vector_type(8))) short short8;
typedef __attribute__((ext_vector_type(4))) float f32x4;

__device__ __forceinline__ unsigned short f2bf(float x) {
    union { float f; unsigned u; } c; c.f = x;
    unsigned u = c.u;
    unsigned r = (u + 0x7fffu + ((u >> 16) & 1u)) >> 16;
    return (unsigned short)r;
}
__device__ __forceinline__ float bf2f(unsigned short h) {
    union { unsigned u; float f; } c; c.u = ((unsigned)h) << 16;
    return c.f;
}
__device__ __forceinline__ float blo(unsigned w) { return bf2f((unsigned short)(w & 0xffffu)); }
__device__ __forceinline__ float bhi(unsigned w) { return bf2f((unsigned short)(w >> 16)); }
__device__ __forceinline__ unsigned bpack(float a, float b) {
    return (unsigned)f2bf(a) | ((unsigned)f2bf(b) << 16);
}

// ---------------- CSR build ----------------

__global__ void k_hist(const int* __restrict__ dst, int* __restrict__ degcnt) {
    int e = blockIdx.x * blockDim.x + threadIdx.x;
    if (e < N_EDGES) atomicAdd(&degcnt[dst[e]], 1);
}

__global__ void k_scan1(const int* __restrict__ deg, int* __restrict__ csum) {
    __shared__ int lds[4];
    int b = blockIdx.x, t = threadIdx.x;
    int base = b * CHUNK + t * 4;
    int s = 0;
    #pragma unroll
    for (int i = 0; i < 4; ++i) {
        int idx = base + i;
        if (idx < N_NODES) s += deg[idx];
    }
    #pragma unroll
    for (int off = 32; off; off >>= 1) s += __shfl_down(s, off, 64);
    int lane = t & 63, w = t >> 6;
    if (lane == 0) lds[w] = s;
    __syncthreads();
    if (t == 0) {
        int tot = 0;
        for (int i = 0; i < 4; ++i) tot += lds[i];
        csum[b] = tot;
    }
}

__global__ void k_scan2(int* __restrict__ csum) {
    __shared__ int lds[NCHUNK];
    int t = threadIdx.x;
    if (t < NCHUNK) lds[t] = csum[t];
    __syncthreads();
    if (t == 0) {
        int run = 0;
        for (int i = 0; i < NCHUNK; ++i) { int v = lds[i]; lds[i] = run; run += v; }
    }
    __syncthreads();
    if (t < NCHUNK) csum[t] = lds[t];
}

__global__ void k_scan3(const int* __restrict__ deg, const int* __restrict__ csum,
                        int* __restrict__ row_ptr) {
    __shared__ int wsum[4];
    int b = blockIdx.x, t = threadIdx.x, lane = t & 63, w = t >> 6;
    int base = b * CHUNK + t * 4;
    int d[4];
    int s = 0;
    #pragma unroll
    for (int i = 0; i < 4; ++i) {
        int idx = base + i;
        d[i] = (idx < N_NODES) ? deg[idx] : 0;
        s += d[i];
    }
    int inc = s;
    #pragma unroll
    for (int off = 1; off < 64; off <<= 1) {
        int v = __shfl_up(inc, off, 64);
        if (lane >= off) inc += v;
    }
    if (lane == 63) wsum[w] = inc;
    int exc = inc - s;
    __syncthreads();
    int woff = 0;
    for (int i = 0; i < w; ++i) woff += wsum[i];
    int run = csum[b] + woff + exc;
    #pragma unroll
    for (int i = 0; i < 4; ++i) {
        int idx = base + i;
        if (idx < N_NODES) row_ptr[idx] = run;
        run += d[i];
    }
    if (b == 0 && t == 0) row_ptr[N_NODES] = N_EDGES;
}

__global__ void k_fill(const int* __restrict__ src, const int* __restrict__ dst,
                       const int* __restrict__ row_ptr, int* __restrict__ fillcnt,
                       int* __restrict__ csr) {
    int e = blockIdx.x * blockDim.x + threadIdx.x;
    if (e < N_EDGES) {
        int d = dst[e];
        int pos = atomicAdd(&fillcnt[d], 1);
        csr[row_ptr[d] + pos] = src[e];
    }
}

// ---------------- feats -> bf16 padded copy [N][80], uint-packed ----------------

__global__ void k_feats_bf(const float* __restrict__ feats, short* __restrict__ fbf) {
    int idx = blockIdx.x * blockDim.x + threadIdx.x;  // uint index
    if (idx >= N_NODES * (FBF_LD / 2)) return;
    int n = idx / (FBF_LD / 2), c2 = idx - n * (FBF_LD / 2);
    int c0 = 2 * c2, c1 = 2 * c2 + 1;
    float v0 = (c0 < F_IN) ? feats[(size_t)n * F_IN + c0] : 0.f;
    float v1 = (c1 < F_IN) ? feats[(size_t)n * F_IN + c1] : 0.f;
    ((unsigned*)fbf)[idx] = bpack(v0, v1);
}

// ---------------- Weight preconvert: Wt[col][k] = [Ws;Wn], bf16 hi/lo ----------------

template <int KP, int K1>
__global__ void k_wconv(const float* __restrict__ Ws, const float* __restrict__ Wn,
                        short* __restrict__ Whi, short* __restrict__ Wlo) {
    int idx = blockIdx.x * blockDim.x + threadIdx.x;
    if (idx >= 112 * KP) return;
    int col = idx / KP, k = idx - col * KP;
    float v = 0.f;
    if (col < HID) {
        if (k < K1) v = Ws[k * HID + col];
        else if (k < 2 * K1) v = Wn[(k - K1) * HID + col];
    }
    unsigned short hi = f2bf(v);
    unsigned short lo = f2bf(v - bf2f(hi));
    Whi[idx] = (short)hi;
    Wlo[idx] = (short)lo;
}

// ---------------- prep1: X1 = [bf16 feats | bf16 mean-agg | 0], uint-packed ----------------
// Gather from fbf [N][80] bf16 (40 uints/row): lane<37 loads one uint (2 feats)/edge, unroll 4.

__global__ void k_prep1(const short* __restrict__ fbf,
                        const int* __restrict__ row_ptr, const int* __restrict__ csr,
                        short* __restrict__ Xhi) {
    __shared__ float tmp[4][80];
    int wid = threadIdx.x >> 6, lane = threadIdx.x & 63;
    int v = blockIdx.x * 4 + wid;
    bool valid = v < N_NODES;
    if (valid && lane < 37) {
        int s = row_ptr[v], e = row_ptr[v + 1];
        const unsigned* fu = (const unsigned*)fbf;
        float a0 = 0.f, a1 = 0.f, b0 = 0.f, b1 = 0.f;
        int j = s;
        for (; j + 3 < e; j += 4) {
            int u0 = csr[j], u1 = csr[j + 1], u2 = csr[j + 2], u3 = csr[j + 3];
            unsigned w0 = fu[(size_t)u0 * (FBF_LD / 2) + lane];
            unsigned w1 = fu[(size_t)u1 * (FBF_LD / 2) + lane];
            unsigned w2 = fu[(size_t)u2 * (FBF_LD / 2) + lane];
            unsigned w3 = fu[(size_t)u3 * (FBF_LD / 2) + lane];
            a0 += blo(w0); a1 += bhi(w0);
            b0 += blo(w1); b1 += bhi(w1);
            a0 += blo(w2); a1 += bhi(w2);
            b0 += blo(w3); b1 += bhi(w3);
        }
        for (; j < e; ++j) {
            unsigned w0 = fu[(size_t)csr[j] * (FBF_LD / 2) + lane];
            a0 += blo(w0); a1 += bhi(w0);
        }
        float inv = 1.0f / fmaxf((float)(e - s), 1.0f);
        tmp[wid][2 * lane] = (a0 + b0) * inv;
        tmp[wid][2 * lane + 1] = (a1 + b1) * inv;
    }
    __syncthreads();
    if (!valid) return;
    unsigned* Xu = (unsigned*)(Xhi + (size_t)v * KP1);            // 80 uints
    const unsigned* su = (const unsigned*)(fbf + (size_t)v * FBF_LD);
    {
        unsigned val;
        if (lane < 37) val = su[lane];                            // self cols 0..73
        else val = bpack(tmp[wid][2 * lane - 74], tmp[wid][2 * lane - 73]);  // agg
        Xu[lane] = val;
    }
    if (lane < 16) {
        int sl = lane + 64;                                       // slots 64..79
        unsigned val = 0;
        if (sl <= 73) val = bpack(tmp[wid][2 * sl - 74], tmp[wid][2 * sl - 73]);
        Xu[sl] = val;
    }
}

// ---------------- prep2: X2[:,100..223] = [bf16 mean-agg h1 | 0], uint-packed ----------------
// Gather from h1c [N][128] bf16 (64 uints/row, 0..49 valid): lane<50, unroll 4.

__global__ void k_prep2(const short* __restrict__ h1c, const int* __restrict__ row_ptr,
                        const int* __restrict__ csr, short* __restrict__ Xhi) {
    __shared__ float tmp[4][100];
    int wid = threadIdx.x >> 6, lane = threadIdx.x & 63;
    int v = blockIdx.x * 4 + wid;
    bool valid = v < N_NODES;
    if (valid && lane < 50) {
        int s = row_ptr[v], e = row_ptr[v + 1];
        const unsigned* hu = (const unsigned*)h1c;
        float a0 = 0.f, a1 = 0.f, b0 = 0.f, b1 = 0.f;
        int j = s;
        for (; j + 3 < e; j += 4) {
            int u0 = csr[j], u1 = csr[j + 1], u2 = csr[j + 2], u3 = csr[j + 3];
            unsigned w0 = hu[(size_t)u0 * (H1C_LD / 2) + lane];
            unsigned w1 = hu[(size_t)u1 * (H1C_LD / 2) + lane];
            unsigned w2 = hu[(size_t)u2 * (H1C_LD / 2) + lane];
            unsigned w3 = hu[(size_t)u3 * (H1C_LD / 2) + lane];
            a0 += blo(w0); a1 += bhi(w0);
            b0 += blo(w1); b1 += bhi(w1);
            a0 += blo(w2); a1 += bhi(w2);
            b0 += blo(w3); b1 += bhi(w3);
        }
        for (; j < e; ++j) {
            unsigned w0 = hu[(size_t)csr[j] * (H1C_LD / 2) + lane];
            a0 += blo(w0); a1 += bhi(w0);
        }
        float inv = 1.0f / fmaxf((float)(e - s), 1.0f);
        tmp[wid][2 * lane] = (a0 + b0) * inv;
        tmp[wid][2 * lane + 1] = (a1 + b1) * inv;
    }
    __syncthreads();
    if (!valid) return;
    unsigned* Xu = (unsigned*)(Xhi + (size_t)v * KP2);  // 112 uints; 0..49 = self (from mfma1)
    if (lane < 62) {
        int sl = 50 + lane;                              // slots 50..111
        unsigned val = 0;
        if (lane < 50) val = bpack(tmp[wid][2 * lane], tmp[wid][2 * lane + 1]);
        Xu[sl] = val;
    }
}

// ---------------- MFMA GEMM: C = relu(X @ Wt^T + bias), X bf16, W hi/lo (bf16x2) ----------------
// LAST=false: write X2hi cols 0..99 + h1c bf16 copy. LAST=true: write Hout fp32 [N,100].

template <int KP, bool LAST>
__global__ __launch_bounds__(256) void k_mfma(
    const short* __restrict__ Xhi,
    const short* __restrict__ Wthi, const short* __restrict__ Wtlo,
    const float* __restrict__ bias,
    short* __restrict__ Yhi, short* __restrict__ h1c, float* __restrict__ Hout) {
    int t = threadIdx.x;
    int wid = t >> 6, lane = t & 63;
    int quad = lane >> 4, lr = lane & 15;
    int rowbase = blockIdx.x * 128 + wid * 32;

    f32x4 acc[2][7];
    #pragma unroll
    for (int rf = 0; rf < 2; ++rf)
        #pragma unroll
        for (int n = 0; n < 7; ++n) acc[rf][n] = (f32x4){0.f, 0.f, 0.f, 0.f};

    const int NC = KP / 32;
    for (int c = 0; c < NC; ++c) {
        short8 ah[2], wh[7], wl[7];
        #pragma unroll
        for (int rf = 0; rf < 2; ++rf) {
            size_t off = (size_t)(rowbase + rf * 16 + lr) * KP + c * 32 + quad * 8;
            ah[rf] = *(const short8*)(Xhi + off);
        }
        #pragma unroll
        for (int n = 0; n < 7; ++n) {
            size_t off = (size_t)(n * 16 + lr) * KP + c * 32 + quad * 8;
            wh[n] = *(const short8*)(Wthi + off);
            wl[n] = *(const short8*)(Wtlo + off);
        }
        #pragma unroll
        for (int rf = 0; rf < 2; ++rf)
            #pragma unroll
            for (int n = 0; n < 7; ++n) {
                acc[rf][n] = __builtin_amdgcn_mfma_f32_16x16x32_bf16(ah[rf], wh[n], acc[rf][n], 0, 0, 0);
                acc[rf][n] = __builtin_amdgcn_mfma_f32_16x16x32_bf16(ah[rf], wl[n], acc[rf][n], 0, 0, 0);
            }
    }

    #pragma unroll
    for (int rf = 0; rf < 2; ++rf) {
        #pragma unroll
        for (int n = 0; n < 7; ++n) {
            int col = n * 16 + lr;
            if (col < HID) {
                float bv = bias[col];
                #pragma unroll
                for (int r = 0; r < 4; ++r) {
                    int row = rowbase + rf * 16 + quad * 4 + r;
                    if (row < N_NODES) {
                        float v = fmaxf(acc[rf][n][r] + bv, 0.f);
                        if (LAST) {
                            Hout[(size_t)row * HID + col] = v;
                        } else {
                            short hv = (short)f2bf(v);
                            Yhi[(size_t)row * KP2 + col] = hv;
                            h1c[(size_t)row * H1C_LD + col] = hv;
                        }
                    }
                }
            }
        }
    }
}

// ---------------- Collapsed predictor head: w_eff[200], b_eff ----------------

__global__ void k_weff(const float* __restrict__ Wp1, const float* __restrict__ bp1,
                       const float* __restrict__ Wp2, const float* __restrict__ bp2,
                       float* __restrict__ weff) {
    int t = threadIdx.x;
    if (t < 200) {
        float s = 0.f;
        for (int k = 0; k < 64; ++k) s += Wp1[t * 64 + k] * Wp2[k];
        weff[t] = s;
    } else if (t == 200) {
        float s = bp2[0];
        for (int k = 0; k < 64; ++k) s += bp1[k] * Wp2[k];
        weff[200] = s;
    }
}

// ---------------- Readout: per-graph weighted sum + max, fused head ----------------

__global__ __launch_bounds__(128) void k_readout(
    const float* __restrict__ h, const int* __restrict__ graph_ids,
    const float* __restrict__ w_atom, const float* __restrict__ b_atom,
    const float* __restrict__ weff, float* __restrict__ out) {
    int g = blockIdx.x;
    int t = threadIdx.x, lane = t & 63, w = t >> 6;

    int s_, e_;
    {
        int l = 0, r = N_NODES;
        while (l < r) { int m = (l + r) >> 1; if (graph_ids[m] < g) l = m + 1; else r = m; }
        s_ = l;
        l = s_; r = N_NODES;
        while (l < r) { int m = (l + r) >> 1; if (graph_ids[m] < g + 1) l = m + 1; else r = m; }
        e_ = l;
    }

    float ba = b_atom[0];
    float wa0 = w_atom[lane];
    float wa1 = (lane < HID - 64) ? w_atom[lane + 64] : 0.f;
    float sum0 = 0.f, sum1 = 0.f, mx0 = 0.f, mx1 = 0.f;  // h >= 0 (relu)
    for (int i = s_ + w; i < e_; i += 2) {
        const float* r = h + (size_t)i * HID;
        float v0 = r[lane];
        float v1 = (lane < HID - 64) ? r[lane + 64] : 0.f;
        float p = v0 * wa0 + v1 * wa1;
        #pragma unroll
        for (int off = 32; off; off >>= 1) p += __shfl_xor(p, off, 64);
        float wt = 1.f / (1.f + __expf(-(p + ba)));
        sum0 += v0 * wt;
        sum1 += v1 * wt;
        mx0 = fmaxf(mx0, v0);
        mx1 = fmaxf(mx1, v1);
    }

    __shared__ float ssum[2][HID];
    __shared__ float smx[2][HID];
    ssum[w][lane] = sum0;
    smx[w][lane] = mx0;
    if (lane < HID - 64) {
        ssum[w][lane + 64] = sum1;
        smx[w][lane + 64] = mx1;
    }
    __syncthreads();

    float contrib = 0.f;
    if (t < HID) {
        float sumf = ssum[0][t] + ssum[1][t];
        float mxf = fmaxf(smx[0][t], smx[1][t]);
        contrib = sumf * weff[t] + mxf * weff[HID + t];
    }
    #pragma unroll
    for (int off = 32; off; off >>= 1) contrib += __shfl_xor(contrib, off, 64);
    __shared__ float red[2];
    if (lane == 0) red[w] = contrib;
    __syncthreads();
    if (t == 0) out[g] = red[0] + red[1] + weff[200];
}

// ---------------- launch ----------------

extern "C" void kernel_launch(void* const* d_in, const int* in_sizes, int n_in,
                              void* d_out, int out_size, void* d_ws, size_t ws_size,
                              hipStream_t stream) {
    const float* node_feats = (const float*)d_in[0];
    const int* src = (const int*)d_in[1];
    const int* dst = (const int*)d_in[2];
    const int* gid = (const int*)d_in[3];
    const float* Ws1 = (const float*)d_in[5];
    const float* Wn1 = (const float*)d_in[6];
    const float* b1 = (const float*)d_in[7];
    const float* Ws2 = (const float*)d_in[8];
    const float* Wn2 = (const float*)d_in[9];
    const float* b2 = (const float*)d_in[10];
    const float* w_atom = (const float*)d_in[11];
    const float* b_atom = (const float*)d_in[12];
    const float* Wp1 = (const float*)d_in[13];
    const float* bp1 = (const float*)d_in[14];
    const float* Wp2 = (const float*)d_in[15];
    const float* bp2 = (const float*)d_in[16];
    float* out = (float*)d_out;

    char* ws = (char*)d_ws;
    size_t off = 0;
    auto alloc = [&](size_t bytes) -> void* {
        void* p = (void*)(ws + off);
        off += (bytes + 255) & ~(size_t)255;
        return p;
    };
    int* degcnt = (int*)alloc(N_NODES * sizeof(int));
    int* fillcnt = (int*)alloc(N_NODES * sizeof(int));
    int* row_ptr = (int*)alloc((N_NODES + 1) * sizeof(int));
    int* csum = (int*)alloc(NCHUNK * sizeof(int));
    int* csr = (int*)alloc((size_t)N_EDGES * sizeof(int));
    short* X1hi = (short*)alloc((size_t)N_PAD * KP1 * sizeof(short));   // 32 MB
    short* X2hi = (short*)alloc((size_t)N_PAD * KP2 * sizeof(short));   // 44.8 MB
    short* h1c = (short*)alloc((size_t)N_NODES * H1C_LD * sizeof(short)); // 25.6 MB
    float* h2 = (float*)alloc((size_t)N_NODES * HID * sizeof(float));   // 40 MB
    short* Wt1hi = (short*)alloc(112 * KP1 * sizeof(short));
    short* Wt1lo = (short*)alloc(112 * KP1 * sizeof(short));
    short* Wt2hi = (short*)alloc(112 * KP2 * sizeof(short));
    short* Wt2lo = (short*)alloc(112 * KP2 * sizeof(short));
    float* weff = (float*)alloc(256 * sizeof(float));
    // fbf (16MB) aliases X2hi (44.8MB): fbf dead after k_prep1, before k_mfma1 writes X2hi.
    short* fbf = X2hi;

    hipMemsetAsync(degcnt, 0, N_NODES * sizeof(int), stream);
    hipMemsetAsync(fillcnt, 0, N_NODES * sizeof(int), stream);

    k_hist<<<(N_EDGES + 255) / 256, 256, 0, stream>>>(dst, degcnt);
    k_scan1<<<NCHUNK, 256, 0, stream>>>(degcnt, csum);
    k_scan2<<<1, 128, 0, stream>>>(csum);
    k_scan3<<<NCHUNK, 256, 0, stream>>>(degcnt, csum, row_ptr);
    k_fill<<<(N_EDGES + 255) / 256, 256, 0, stream>>>(src, dst, row_ptr, fillcnt, csr);

    k_feats_bf<<<(N_NODES * (FBF_LD / 2) + 255) / 256, 256, 0, stream>>>(node_feats, fbf);
    k_wconv<KP1, F_IN><<<(112 * KP1 + 255) / 256, 256, 0, stream>>>(Ws1, Wn1, Wt1hi, Wt1lo);
    k_wconv<KP2, HID><<<(112 * KP2 + 255) / 256, 256, 0, stream>>>(Ws2, Wn2, Wt2hi, Wt2lo);

    k_prep1<<<(N_NODES + 3) / 4, 256, 0, stream>>>(fbf, row_ptr, csr, X1hi);
    k_mfma<KP1, false><<<N_PAD / 128, 256, 0, stream>>>(X1hi, Wt1hi, Wt1lo, b1,
                                                        X2hi, h1c, nullptr);
    k_prep2<<<(N_NODES + 3) / 4, 256, 0, stream>>>(h1c, row_ptr, csr, X2hi);
    k_mfma<KP2, true><<<N_PAD / 128, 256, 0, stream>>>(X2hi, Wt2hi, Wt2lo, b2,
                                                       nullptr, nullptr, h2);

    k_weff<<<1, 256, 0, stream>>>(Wp1, bp1, Wp2, bp2, weff);
    k_readout<<<N_GRAPHS, 128, 0, stream>>>(h2, gid, w_atom, b_atom, weff, out);
}

// Round 6
// 420.234 us; speedup vs baseline: 2.0637x; 1.1045x over previous
//
#include <hip/hip_runtime.h>

#define N_NODES 100000
#define N_PAD   100096   // 782 blocks * 128 rows
#define N_EDGES 1600000
#define N_GRAPHS 1024
#define F_IN 74
#define HID 100

#define KP1 160   // 74+74 -> pad to 5*32
#define KP2 224   // 100+100 -> pad to 7*32

#define FBF_LD 80   // bf16 feats copy row stride (shorts)
#define H1C_LD 128  // bf16 h1 copy row stride (shorts), 256B aligned rows

#define CHUNK 1024
#define NCHUNK ((N_NODES + CHUNK - 1) / CHUNK)  // 98

#define NB ((N_NODES + 255) / 256)   // 391 dst-buckets of 256 nodes
#define BIN_EPB 4096                 // edges per k_bin block
#define NBB ((N_EDGES + BIN_EPB - 1) / BIN_EPB)

typedef __attribute__((ext_vector_type(8))) short short8;
typedef __attribute__((ext_vector_type(4))) float f32x4;

__device__ __forceinline__ unsigned short f2bf(float x) {
    union { float f; unsigned u; } c; c.f = x;
    unsigned u = c.u;
    unsigned r = (u + 0x7fffu + ((u >> 16) & 1u)) >> 16;
    return (unsigned short)r;
}
__device__ __forceinline__ float bf2f(unsigned short h) {
    union { unsigned u; float f; } c; c.u = ((unsigned)h) << 16;
    return c.f;
}
__device__ __forceinline__ float blo(unsigned w) { return bf2f((unsigned short)(w & 0xffffu)); }
__device__ __forceinline__ float bhi(unsigned w) { return bf2f((unsigned short)(w >> 16)); }
__device__ __forceinline__ unsigned bpack(float a, float b) {
    return (unsigned)f2bf(a) | ((unsigned)f2bf(b) << 16);
}

// ---------------- degree histogram + scan (row_ptr) ----------------

__global__ void k_hist(const int* __restrict__ dst, int* __restrict__ degcnt) {
    int e = blockIdx.x * blockDim.x + threadIdx.x;
    if (e < N_EDGES) atomicAdd(&degcnt[dst[e]], 1);
}

__global__ void k_scan1(const int* __restrict__ deg, int* __restrict__ csum) {
    __shared__ int lds[4];
    int b = blockIdx.x, t = threadIdx.x;
    int base = b * CHUNK + t * 4;
    int s = 0;
    #pragma unroll
    for (int i = 0; i < 4; ++i) {
        int idx = base + i;
        if (idx < N_NODES) s += deg[idx];
    }
    #pragma unroll
    for (int off = 32; off; off >>= 1) s += __shfl_down(s, off, 64);
    int lane = t & 63, w = t >> 6;
    if (lane == 0) lds[w] = s;
    __syncthreads();
    if (t == 0) {
        int tot = 0;
        for (int i = 0; i < 4; ++i) tot += lds[i];
        csum[b] = tot;
    }
}

__global__ void k_scan2(int* __restrict__ csum) {
    __shared__ int lds[NCHUNK];
    int t = threadIdx.x;
    if (t < NCHUNK) lds[t] = csum[t];
    __syncthreads();
    if (t == 0) {
        int run = 0;
        for (int i = 0; i < NCHUNK; ++i) { int v = lds[i]; lds[i] = run; run += v; }
    }
    __syncthreads();
    if (t < NCHUNK) csum[t] = lds[t];
}

__global__ void k_scan3(const int* __restrict__ deg, const int* __restrict__ csum,
                        int* __restrict__ row_ptr) {
    __shared__ int wsum[4];
    int b = blockIdx.x, t = threadIdx.x, lane = t & 63, w = t >> 6;
    int base = b * CHUNK + t * 4;
    int d[4];
    int s = 0;
    #pragma unroll
    for (int i = 0; i < 4; ++i) {
        int idx = base + i;
        d[i] = (idx < N_NODES) ? deg[idx] : 0;
        s += d[i];
    }
    int inc = s;
    #pragma unroll
    for (int off = 1; off < 64; off <<= 1) {
        int v = __shfl_up(inc, off, 64);
        if (lane >= off) inc += v;
    }
    if (lane == 63) wsum[w] = inc;
    int exc = inc - s;
    __syncthreads();
    int woff = 0;
    for (int i = 0; i < w; ++i) woff += wsum[i];
    int run = csum[b] + woff + exc;
    #pragma unroll
    for (int i = 0; i < 4; ++i) {
        int idx = base + i;
        if (idx < N_NODES) row_ptr[idx] = run;
        run += d[i];
    }
    if (b == 0 && t == 0) row_ptr[N_NODES] = N_EDGES;
}

// ---------------- binned CSR fill: k_bin (edge->bucket runs) + k_scatter ----------------
// bucket b = dst>>8; bucket region in bbuf/csr = [row_ptr[b<<8], row_ptr[(b+1)<<8]).

__global__ __launch_bounds__(256) void k_bin(const int* __restrict__ src,
                                             const int* __restrict__ dst,
                                             const int* __restrict__ row_ptr,
                                             int* __restrict__ bucket_fill,
                                             uint2* __restrict__ bbuf) {
    __shared__ int cnt[NB];
    __shared__ int base[NB];
    __shared__ int bs[NB];
    int t = threadIdx.x;
    for (int i = t; i < NB; i += 256) {
        cnt[i] = 0;
        int n0 = i << 8;
        bs[i] = row_ptr[n0];
    }
    __syncthreads();
    int e0 = blockIdx.x * BIN_EPB;
    int e1 = e0 + BIN_EPB < N_EDGES ? e0 + BIN_EPB : N_EDGES;
    // phase 1: local bucket counts
    for (int e = e0 + t; e < e1; e += 256) {
        atomicAdd(&cnt[dst[e] >> 8], 1);
    }
    __syncthreads();
    // phase 2: reserve global space per bucket; reset cnt
    for (int i = t; i < NB; i += 256) {
        int c = cnt[i];
        base[i] = c ? atomicAdd(&bucket_fill[i], c) : 0;
        cnt[i] = 0;
    }
    __syncthreads();
    // phase 3: append (src,dst) into this block's run per bucket
    for (int e = e0 + t; e < e1; e += 256) {
        int d = dst[e];
        int b = d >> 8;
        int pos = atomicAdd(&cnt[b], 1);
        bbuf[(size_t)bs[b] + base[b] + pos] = (uint2){(unsigned)src[e], (unsigned)d};
    }
}

__global__ __launch_bounds__(256) void k_scatter(const uint2* __restrict__ bbuf,
                                                 const int* __restrict__ row_ptr,
                                                 int* __restrict__ csr) {
    __shared__ int fc[256];
    __shared__ int rp[257];
    int b = blockIdx.x, t = threadIdx.x;
    int nstart = b << 8;
    int nend = nstart + 256 < N_NODES ? nstart + 256 : N_NODES;
    fc[t] = 0;
    if (nstart + t <= nend) rp[t] = row_ptr[nstart + t];
    if (t == 0 && nend - nstart == 256) rp[256] = row_ptr[nend];
    __syncthreads();
    int s = rp[0];
    int e = rp[nend - nstart];
    for (int i = s + t; i < e; i += 256) {
        uint2 p = bbuf[i];
        int dl = (int)p.y - nstart;
        int pos = atomicAdd(&fc[dl], 1);
        csr[rp[dl] + pos] = (int)p.x;
    }
}

// ---------------- feats -> bf16 padded copy [N][80], uint-packed ----------------

__global__ void k_feats_bf(const float* __restrict__ feats, short* __restrict__ fbf) {
    int idx = blockIdx.x * blockDim.x + threadIdx.x;  // uint index
    if (idx >= N_NODES * (FBF_LD / 2)) return;
    int n = idx / (FBF_LD / 2), c2 = idx - n * (FBF_LD / 2);
    int c0 = 2 * c2, c1 = 2 * c2 + 1;
    float v0 = (c0 < F_IN) ? feats[(size_t)n * F_IN + c0] : 0.f;
    float v1 = (c1 < F_IN) ? feats[(size_t)n * F_IN + c1] : 0.f;
    ((unsigned*)fbf)[idx] = bpack(v0, v1);
}

// ---------------- Weight preconvert: Wt[col][k] = [Ws;Wn], bf16 hi/lo ----------------

template <int KP, int K1>
__global__ void k_wconv(const float* __restrict__ Ws, const float* __restrict__ Wn,
                        short* __restrict__ Whi, short* __restrict__ Wlo) {
    int idx = blockIdx.x * blockDim.x + threadIdx.x;
    if (idx >= 112 * KP) return;
    int col = idx / KP, k = idx - col * KP;
    float v = 0.f;
    if (col < HID) {
        if (k < K1) v = Ws[k * HID + col];
        else if (k < 2 * K1) v = Wn[(k - K1) * HID + col];
    }
    unsigned short hi = f2bf(v);
    unsigned short lo = f2bf(v - bf2f(hi));
    Whi[idx] = (short)hi;
    Wlo[idx] = (short)lo;
}

// ---------------- prep1: X1 = [bf16 feats | bf16 mean-agg | 0], uint-packed ----------------
// Gather from fbf [N][80] bf16 (40 uints/row): lane<37 loads one uint/edge, unroll 8.

__global__ void k_prep1(const short* __restrict__ fbf,
                        const int* __restrict__ row_ptr, const int* __restrict__ csr,
                        short* __restrict__ Xhi) {
    __shared__ float tmp[4][80];
    int wid = threadIdx.x >> 6, lane = threadIdx.x & 63;
    int v = blockIdx.x * 4 + wid;
    bool valid = v < N_NODES;
    if (valid && lane < 37) {
        int s = row_ptr[v], e = row_ptr[v + 1];
        const unsigned* fu = (const unsigned*)fbf;
        float a0 = 0.f, a1 = 0.f, b0 = 0.f, b1 = 0.f;
        int j = s;
        for (; j + 7 < e; j += 8) {
            unsigned w0 = fu[(size_t)csr[j] * (FBF_LD / 2) + lane];
            unsigned w1 = fu[(size_t)csr[j + 1] * (FBF_LD / 2) + lane];
            unsigned w2 = fu[(size_t)csr[j + 2] * (FBF_LD / 2) + lane];
            unsigned w3 = fu[(size_t)csr[j + 3] * (FBF_LD / 2) + lane];
            unsigned w4 = fu[(size_t)csr[j + 4] * (FBF_LD / 2) + lane];
            unsigned w5 = fu[(size_t)csr[j + 5] * (FBF_LD / 2) + lane];
            unsigned w6 = fu[(size_t)csr[j + 6] * (FBF_LD / 2) + lane];
            unsigned w7 = fu[(size_t)csr[j + 7] * (FBF_LD / 2) + lane];
            a0 += blo(w0); a1 += bhi(w0);
            b0 += blo(w1); b1 += bhi(w1);
            a0 += blo(w2); a1 += bhi(w2);
            b0 += blo(w3); b1 += bhi(w3);
            a0 += blo(w4); a1 += bhi(w4);
            b0 += blo(w5); b1 += bhi(w5);
            a0 += blo(w6); a1 += bhi(w6);
            b0 += blo(w7); b1 += bhi(w7);
        }
        for (; j < e; ++j) {
            unsigned w0 = fu[(size_t)csr[j] * (FBF_LD / 2) + lane];
            a0 += blo(w0); a1 += bhi(w0);
        }
        float inv = 1.0f / fmaxf((float)(e - s), 1.0f);
        tmp[wid][2 * lane] = (a0 + b0) * inv;
        tmp[wid][2 * lane + 1] = (a1 + b1) * inv;
    }
    __syncthreads();
    if (!valid) return;
    unsigned* Xu = (unsigned*)(Xhi + (size_t)v * KP1);            // 80 uints
    const unsigned* su = (const unsigned*)(fbf + (size_t)v * FBF_LD);
    {
        unsigned val;
        if (lane < 37) val = su[lane];                            // self cols 0..73
        else val = bpack(tmp[wid][2 * lane - 74], tmp[wid][2 * lane - 73]);  // agg
        Xu[lane] = val;
    }
    if (lane < 16) {
        int sl = lane + 64;                                       // slots 64..79
        unsigned val = 0;
        if (sl <= 73) val = bpack(tmp[wid][2 * sl - 74], tmp[wid][2 * sl - 73]);
        Xu[sl] = val;
    }
}

// ---------------- prep2: X2[:,100..223] = [bf16 mean-agg h1 | 0], uint-packed ----------------
// Gather from h1c [N][128] bf16 (64 uints/row, 0..49 valid): lane<50, unroll 8.

__global__ void k_prep2(const short* __restrict__ h1c, const int* __restrict__ row_ptr,
                        const int* __restrict__ csr, short* __restrict__ Xhi) {
    __shared__ float tmp[4][100];
    int wid = threadIdx.x >> 6, lane = threadIdx.x & 63;
    int v = blockIdx.x * 4 + wid;
    bool valid = v < N_NODES;
    if (valid && lane < 50) {
        int s = row_ptr[v], e = row_ptr[v + 1];
        const unsigned* hu = (const unsigned*)h1c;
        float a0 = 0.f, a1 = 0.f, b0 = 0.f, b1 = 0.f;
        int j = s;
        for (; j + 7 < e; j += 8) {
            unsigned w0 = hu[(size_t)csr[j] * (H1C_LD / 2) + lane];
            unsigned w1 = hu[(size_t)csr[j + 1] * (H1C_LD / 2) + lane];
            unsigned w2 = hu[(size_t)csr[j + 2] * (H1C_LD / 2) + lane];
            unsigned w3 = hu[(size_t)csr[j + 3] * (H1C_LD / 2) + lane];
            unsigned w4 = hu[(size_t)csr[j + 4] * (H1C_LD / 2) + lane];
            unsigned w5 = hu[(size_t)csr[j + 5] * (H1C_LD / 2) + lane];
            unsigned w6 = hu[(size_t)csr[j + 6] * (H1C_LD / 2) + lane];
            unsigned w7 = hu[(size_t)csr[j + 7] * (H1C_LD / 2) + lane];
            a0 += blo(w0); a1 += bhi(w0);
            b0 += blo(w1); b1 += bhi(w1);
            a0 += blo(w2); a1 += bhi(w2);
            b0 += blo(w3); b1 += bhi(w3);
            a0 += blo(w4); a1 += bhi(w4);
            b0 += blo(w5); b1 += bhi(w5);
            a0 += blo(w6); a1 += bhi(w6);
            b0 += blo(w7); b1 += bhi(w7);
        }
        for (; j < e; ++j) {
            unsigned w0 = hu[(size_t)csr[j] * (H1C_LD / 2) + lane];
            a0 += blo(w0); a1 += bhi(w0);
        }
        float inv = 1.0f / fmaxf((float)(e - s), 1.0f);
        tmp[wid][2 * lane] = (a0 + b0) * inv;
        tmp[wid][2 * lane + 1] = (a1 + b1) * inv;
    }
    __syncthreads();
    if (!valid) return;
    unsigned* Xu = (unsigned*)(Xhi + (size_t)v * KP2);  // 112 uints; 0..49 = self (from mfma1)
    if (lane < 62) {
        int sl = 50 + lane;                              // slots 50..111
        unsigned val = 0;
        if (lane < 50) val = bpack(tmp[wid][2 * lane], tmp[wid][2 * lane + 1]);
        Xu[sl] = val;
    }
}

// ---------------- MFMA GEMM: C = relu(X @ Wt^T + bias), X bf16, W hi/lo (bf16x2) ----------------
// LAST=false: write X2hi cols 0..99 + h1c bf16 copy. LAST=true: write Hout fp32 [N,100].

template <int KP, bool LAST>
__global__ __launch_bounds__(256) void k_mfma(
    const short* __restrict__ Xhi,
    const short* __restrict__ Wthi, const short* __restrict__ Wtlo,
    const float* __restrict__ bias,
    short* __restrict__ Yhi, short* __restrict__ h1c, float* __restrict__ Hout) {
    int t = threadIdx.x;
    int wid = t >> 6, lane = t & 63;
    int quad = lane >> 4, lr = lane & 15;
    int rowbase = blockIdx.x * 128 + wid * 32;

    f32x4 acc[2][7];
    #pragma unroll
    for (int rf = 0; rf < 2; ++rf)
        #pragma unroll
        for (int n = 0; n < 7; ++n) acc[rf][n] = (f32x4){0.f, 0.f, 0.f, 0.f};

    const int NC = KP / 32;
    for (int c = 0; c < NC; ++c) {
        short8 ah[2], wh[7], wl[7];
        #pragma unroll
        for (int rf = 0; rf < 2; ++rf) {
            size_t off = (size_t)(rowbase + rf * 16 + lr) * KP + c * 32 + quad * 8;
            ah[rf] = *(const short8*)(Xhi + off);
        }
        #pragma unroll
        for (int n = 0; n < 7; ++n) {
            size_t off = (size_t)(n * 16 + lr) * KP + c * 32 + quad * 8;
            wh[n] = *(const short8*)(Wthi + off);
            wl[n] = *(const short8*)(Wtlo + off);
        }
        #pragma unroll
        for (int rf = 0; rf < 2; ++rf)
            #pragma unroll
            for (int n = 0; n < 7; ++n) {
                acc[rf][n] = __builtin_amdgcn_mfma_f32_16x16x32_bf16(ah[rf], wh[n], acc[rf][n], 0, 0, 0);
                acc[rf][n] = __builtin_amdgcn_mfma_f32_16x16x32_bf16(ah[rf], wl[n], acc[rf][n], 0, 0, 0);
            }
    }

    #pragma unroll
    for (int rf = 0; rf < 2; ++rf) {
        #pragma unroll
        for (int n = 0; n < 7; ++n) {
            int col = n * 16 + lr;
            if (col < HID) {
                float bv = bias[col];
                #pragma unroll
                for (int r = 0; r < 4; ++r) {
                    int row = rowbase + rf * 16 + quad * 4 + r;
                    if (row < N_NODES) {
                        float v = fmaxf(acc[rf][n][r] + bv, 0.f);
                        if (LAST) {
                            Hout[(size_t)row * HID + col] = v;
                        } else {
                            short hv = (short)f2bf(v);
                            Yhi[(size_t)row * KP2 + col] = hv;
                            h1c[(size_t)row * H1C_LD + col] = hv;
                        }
                    }
                }
            }
        }
    }
}

// ---------------- Collapsed predictor head: w_eff[200], b_eff ----------------

__global__ void k_weff(const float* __restrict__ Wp1, const float* __restrict__ bp1,
                       const float* __restrict__ Wp2, const float* __restrict__ bp2,
                       float* __restrict__ weff) {
    int t = threadIdx.x;
    if (t < 200) {
        float s = 0.f;
        for (int k = 0; k < 64; ++k) s += Wp1[t * 64 + k] * Wp2[k];
        weff[t] = s;
    } else if (t == 200) {
        float s = bp2[0];
        for (int k = 0; k < 64; ++k) s += bp1[k] * Wp2[k];
        weff[200] = s;
    }
}

// ---------------- Readout: per-graph weighted sum + max, fused head ----------------

__global__ __launch_bounds__(128) void k_readout(
    const float* __restrict__ h, const int* __restrict__ graph_ids,
    const float* __restrict__ w_atom, const float* __restrict__ b_atom,
    const float* __restrict__ weff, float* __restrict__ out) {
    int g = blockIdx.x;
    int t = threadIdx.x, lane = t & 63, w = t >> 6;

    int s_, e_;
    {
        int l = 0, r = N_NODES;
        while (l < r) { int m = (l + r) >> 1; if (graph_ids[m] < g) l = m + 1; else r = m; }
        s_ = l;
        l = s_; r = N_NODES;
        while (l < r) { int m = (l + r) >> 1; if (graph_ids[m] < g + 1) l = m + 1; else r = m; }
        e_ = l;
    }

    float ba = b_atom[0];
    float wa0 = w_atom[lane];
    float wa1 = (lane < HID - 64) ? w_atom[lane + 64] : 0.f;
    float sum0 = 0.f, sum1 = 0.f, mx0 = 0.f, mx1 = 0.f;  // h >= 0 (relu)
    for (int i = s_ + w; i < e_; i += 2) {
        const float* r = h + (size_t)i * HID;
        float v0 = r[lane];
        float v1 = (lane < HID - 64) ? r[lane + 64] : 0.f;
        float p = v0 * wa0 + v1 * wa1;
        #pragma unroll
        for (int off = 32; off; off >>= 1) p += __shfl_xor(p, off, 64);
        float wt = 1.f / (1.f + __expf(-(p + ba)));
        sum0 += v0 * wt;
        sum1 += v1 * wt;
        mx0 = fmaxf(mx0, v0);
        mx1 = fmaxf(mx1, v1);
    }

    __shared__ float ssum[2][HID];
    __shared__ float smx[2][HID];
    ssum[w][lane] = sum0;
    smx[w][lane] = mx0;
    if (lane < HID - 64) {
        ssum[w][lane + 64] = sum1;
        smx[w][lane + 64] = mx1;
    }
    __syncthreads();

    float contrib = 0.f;
    if (t < HID) {
        float sumf = ssum[0][t] + ssum[1][t];
        float mxf = fmaxf(smx[0][t], smx[1][t]);
        contrib = sumf * weff[t] + mxf * weff[HID + t];
    }
    #pragma unroll
    for (int off = 32; off; off >>= 1) contrib += __shfl_xor(contrib, off, 64);
    __shared__ float red[2];
    if (lane == 0) red[w] = contrib;
    __syncthreads();
    if (t == 0) out[g] = red[0] + red[1] + weff[200];
}

// ---------------- launch ----------------

extern "C" void kernel_launch(void* const* d_in, const int* in_sizes, int n_in,
                              void* d_out, int out_size, void* d_ws, size_t ws_size,
                              hipStream_t stream) {
    const float* node_feats = (const float*)d_in[0];
    const int* src = (const int*)d_in[1];
    const int* dst = (const int*)d_in[2];
    const int* gid = (const int*)d_in[3];
    const float* Ws1 = (const float*)d_in[5];
    const float* Wn1 = (const float*)d_in[6];
    const float* b1 = (const float*)d_in[7];
    const float* Ws2 = (const float*)d_in[8];
    const float* Wn2 = (const float*)d_in[9];
    const float* b2 = (const float*)d_in[10];
    const float* w_atom = (const float*)d_in[11];
    const float* b_atom = (const float*)d_in[12];
    const float* Wp1 = (const float*)d_in[13];
    const float* bp1 = (const float*)d_in[14];
    const float* Wp2 = (const float*)d_in[15];
    const float* bp2 = (const float*)d_in[16];
    float* out = (float*)d_out;

    char* ws = (char*)d_ws;
    size_t off = 0;
    auto alloc = [&](size_t bytes) -> void* {
        void* p = (void*)(ws + off);
        off += (bytes + 255) & ~(size_t)255;
        return p;
    };
    int* degcnt = (int*)alloc(N_NODES * sizeof(int));
    int* row_ptr = (int*)alloc((N_NODES + 1) * sizeof(int));
    int* csum = (int*)alloc(NCHUNK * sizeof(int));
    int* bucket_fill = (int*)alloc(NB * sizeof(int));
    int* csr = (int*)alloc((size_t)N_EDGES * sizeof(int));
    uint2* bbuf = (uint2*)alloc((size_t)N_EDGES * sizeof(uint2));         // 12.8 MB
    short* X1hi = (short*)alloc((size_t)N_PAD * KP1 * sizeof(short));     // 32 MB
    short* X2hi = (short*)alloc((size_t)N_PAD * KP2 * sizeof(short));     // 44.8 MB
    short* h1c = (short*)alloc((size_t)N_NODES * H1C_LD * sizeof(short)); // 25.6 MB
    float* h2 = (float*)alloc((size_t)N_NODES * HID * sizeof(float));     // 40 MB
    short* Wt1hi = (short*)alloc(112 * KP1 * sizeof(short));
    short* Wt1lo = (short*)alloc(112 * KP1 * sizeof(short));
    short* Wt2hi = (short*)alloc(112 * KP2 * sizeof(short));
    short* Wt2lo = (short*)alloc(112 * KP2 * sizeof(short));
    float* weff = (float*)alloc(256 * sizeof(float));
    // fbf (16MB) aliases X2hi (44.8MB): fbf dead after k_prep1, before k_mfma1 writes X2hi.
    short* fbf = X2hi;

    hipMemsetAsync(degcnt, 0, N_NODES * sizeof(int), stream);
    hipMemsetAsync(bucket_fill, 0, NB * sizeof(int), stream);

    k_hist<<<(N_EDGES + 255) / 256, 256, 0, stream>>>(dst, degcnt);
    k_scan1<<<NCHUNK, 256, 0, stream>>>(degcnt, csum);
    k_scan2<<<1, 128, 0, stream>>>(csum);
    k_scan3<<<NCHUNK, 256, 0, stream>>>(degcnt, csum, row_ptr);
    k_bin<<<NBB, 256, 0, stream>>>(src, dst, row_ptr, bucket_fill, bbuf);
    k_scatter<<<NB, 256, 0, stream>>>(bbuf, row_ptr, csr);

    k_feats_bf<<<(N_NODES * (FBF_LD / 2) + 255) / 256, 256, 0, stream>>>(node_feats, fbf);
    k_wconv<KP1, F_IN><<<(112 * KP1 + 255) / 256, 256, 0, stream>>>(Ws1, Wn1, Wt1hi, Wt1lo);
    k_wconv<KP2, HID><<<(112 * KP2 + 255) / 256, 256, 0, stream>>>(Ws2, Wn2, Wt2hi, Wt2lo);

    k_prep1<<<(N_NODES + 3) / 4, 256, 0, stream>>>(fbf, row_ptr, csr, X1hi);
    k_mfma<KP1, false><<<N_PAD / 128, 256, 0, stream>>>(X1hi, Wt1hi, Wt1lo, b1,
                                                        X2hi, h1c, nullptr);
    k_prep2<<<(N_NODES + 3) / 4, 256, 0, stream>>>(h1c, row_ptr, csr, X2hi);
    k_mfma<KP2, true><<<N_PAD / 128, 256, 0, stream>>>(X2hi, Wt2hi, Wt2lo, b2,
                                                       nullptr, nullptr, h2);

    k_weff<<<1, 256, 0, stream>>>(Wp1, bp1, Wp2, bp2, weff);
    k_readout<<<N_GRAPHS, 128, 0, stream>>>(h2, gid, w_atom, b_atom, weff, out);
}